// Round 12
// baseline (443.222 us; speedup 1.0000x reference)
//
#include <hip/hip_runtime.h>

// Decoder via bf16 hi/lo-split MFMA implicit GEMM.
//   fp32 v = hi(bf16) + lo(bf16);  A*B ~= Ah*Bh + Ah*Bl + Al*Bh  (3x mfma_f32_16x16x32_bf16)
// conv_transpose SAME:
//   stride1: O[o] = sum_k W[k] X[o+k-1]
//   stride2, parity r: r==1 -> tap kd=1,id=i ; r==0 -> kd=2,id=i and kd=0,id=i-1  (o=2i+r)
// Weights DHWIO [tap][ci][co], activations NDHWC, hi/lo separate arrays.
// MFMA layouts (verified): A[m=lane&15][k=(lane>>4)*8+j], B[n=lane&15][k=(lane>>4)*8+j],
// D: col=lane&15, row=(lane>>4)*4+reg.
// LDS rule (R10 lesson): voxel slot stride must be a multiple of 8 u16 (16B) or b128
// LDS ops get split by HW. VST=72.
//
// Round12: L4 (worst layer vs the ~41% plateau: ~28%) -> deconv_s2_lds: all parities of
// one rd-group share the block's LDS-staged A slab (stride-2 parities all read the SAME
// input). Two launches (RD=0: 2 planes/18 taps, RD=1: 1 plane/9 taps) keep the tap list
// constexpr and acc at 64 VGPR. Wave = one 16-voxel m-tile x all 4 cout granules ->
// A-LDS reads 2/tap/wave. Everything else identical to R11.

typedef __attribute__((ext_vector_type(8))) short bf16x8;
typedef __attribute__((ext_vector_type(4))) float f32x4;
typedef unsigned short u16;

__device__ __forceinline__ u16 f2bf(float f) {
    unsigned u = __builtin_bit_cast(unsigned, f);
    u += 0x7fffu + ((u >> 16) & 1u);
    return (u16)(u >> 16);
}
__device__ __forceinline__ float bf2f(u16 h) {
    unsigned u = ((unsigned)h) << 16;
    return __builtin_bit_cast(float, u);
}
__device__ __forceinline__ void split_store(float v, u16* ph, u16* pl) {
    u16 h = f2bf(v);
    *ph = h;
    *pl = f2bf(v - bf2f(h));
}
__device__ __forceinline__ int rfl(int v) { return __builtin_amdgcn_readfirstlane(v); }
__device__ __forceinline__ int swz(int bx, int G) { return (bx & 7) * (G >> 3) + (bx >> 3); }

__global__ __launch_bounds__(256) void zero4k(float* z) {
    ((float4*)z)[threadIdx.x] = make_float4(0.f, 0.f, 0.f, 0.f);
}

__global__ __launch_bounds__(256) void split_x(
    const float* __restrict__ x, u16* __restrict__ Xh, u16* __restrict__ Xl)
{
    const int i = (blockIdx.x * 256 + threadIdx.x) * 4;
    const float4 v = *(const float4*)(x + i);
    split_store(v.x, Xh + i,     Xl + i);
    split_store(v.y, Xh + i + 1, Xl + i + 1);
    split_store(v.z, Xh + i + 2, Xl + i + 2);
    split_store(v.w, Xh + i + 3, Xl + i + 3);
}

// pack fp32 w[27][Cin][Cout] -> bf16 hi/lo frags, layout [tap][nt][kc][lane][8].
__global__ __launch_bounds__(256) void pack_all(
    const float* __restrict__ w0_, const float* __restrict__ w1_,
    const float* __restrict__ w2_, const float* __restrict__ w3_,
    const float* __restrict__ w4_, const float* __restrict__ w5_,
    u16* s0h, u16* s0l, u16* s1h, u16* s1l, u16* s2h, u16* s2l,
    u16* s3h, u16* s3l, u16* s4h, u16* s4l, u16* s5h, u16* s5l)
{
    const float* w; u16 *bh, *bl; int Cin, Cout, nNt;
    switch (blockIdx.y) {
        case 0: w = w0_; bh = s0h; bl = s0l; Cin = 128; Cout = 128; nNt = 8; break;
        case 1: w = w1_; bh = s1h; bl = s1l; Cin = 128; Cout = 128; nNt = 8; break;
        case 2: w = w2_; bh = s2h; bl = s2l; Cin = 128; Cout = 128; nNt = 8; break;
        case 3: w = w3_; bh = s3h; bl = s3l; Cin = 128; Cout = 128; nNt = 8; break;
        case 4: w = w4_; bh = s4h; bl = s4l; Cin = 128; Cout = 64;  nNt = 4; break;
        default:w = w5_; bh = s5h; bl = s5l; Cin = 64;  Cout = 3;   nNt = 1; break;
    }
    const int KC = Cin >> 5;
    const int total = 27 * nNt * KC * 64;
    int t = blockIdx.x * 256 + threadIdx.x;
    if (t >= total) return;
    const int lane = t & 63;
    int r = t >> 6;
    const int kc = r % KC; r /= KC;
    const int nt = r % nNt; r /= nNt;
    const int tap = r;
    const int n  = nt * 16 + (lane & 15);
    const int k0 = kc * 32 + (lane >> 4) * 8;
    const size_t o = (size_t)t * 8;
    for (int j = 0; j < 8; ++j) {
        float v = (n < Cout) ? w[((size_t)tap * Cin + k0 + j) * Cout + n] : 0.f;
        u16 h = f2bf(v);
        bh[o + j] = h;
        bl[o + j] = f2bf(v - bf2f(h));
    }
}

// ---------- stride-1 MFMA conv, register-double-buffered K-loop (R7) ----------
template<int CIN, int MT, int NT, bool RELU>
__global__ __launch_bounds__(64) void conv_s1_mfma(
    const u16* __restrict__ Ah, const u16* __restrict__ Al,
    const u16* __restrict__ Bh, const u16* __restrict__ Bl,
    const float* __restrict__ bias, const u16* __restrict__ Z,
    u16* __restrict__ Yh, u16* __restrict__ Yl,
    int D, int lD, int Cout, int nNtTot)
{
    constexpr int KC = CIN >> 5;
    const int lane = threadIdx.x;
    const int ml = lane & 15, kq = lane >> 4;
    const int M0 = swz(blockIdx.x, gridDim.x) * (MT * 16);
    const int N0t = blockIdx.y * NT;

    int vw[MT], vh[MT], vd[MT];
    #pragma unroll
    for (int mt = 0; mt < MT; ++mt) {
        const int vox = M0 + mt * 16 + ml;
        vw[mt] = vox & (D - 1); vh[mt] = (vox >> lD) & (D - 1); vd[mt] = vox >> (2 * lD);
    }

    f32x4 acc[MT][NT];
    #pragma unroll
    for (int nt = 0; nt < NT; ++nt) {
        const float bv = bias[(N0t + nt) * 16 + ml];
        #pragma unroll
        for (int mt = 0; mt < MT; ++mt) acc[mt][nt] = (f32x4){bv, bv, bv, bv};
    }

    const u16 *pah[MT], *pal[MT];
    size_t fb;
    auto set_tap = [&](int tap) {
        const int kd = tap / 9, kh = (tap % 9) / 3, kw = tap % 3;
        #pragma unroll
        for (int mt = 0; mt < MT; ++mt) {
            const int id = vd[mt] + kd - 1, ih = vh[mt] + kh - 1, iw = vw[mt] + kw - 1;
            const bool v = (unsigned)id < (unsigned)D && (unsigned)ih < (unsigned)D &&
                           (unsigned)iw < (unsigned)D;
            const size_t off = (size_t)((id * D + ih) * D + iw) * CIN;
            pah[mt] = v ? Ah + off : Z;
            pal[mt] = v ? Al + off : Z;
        }
        fb = ((size_t)tap * nNtTot + N0t) * KC;
    };

    bf16x8 fah[2][MT], fal[2][MT], fbh[2][NT], fbl[2][NT];
    auto load_frags = [&](int buf, int kc) {
        const int ko = kc * 32 + kq * 8;
        #pragma unroll
        for (int mt = 0; mt < MT; ++mt) {
            fah[buf][mt] = *(const bf16x8*)(pah[mt] + ko);
            fal[buf][mt] = *(const bf16x8*)(pal[mt] + ko);
        }
        #pragma unroll
        for (int nt = 0; nt < NT; ++nt) {
            const size_t fo = (fb + (size_t)nt * KC + kc) * 512 + lane * 8;
            fbh[buf][nt] = *(const bf16x8*)(Bh + fo);
            fbl[buf][nt] = *(const bf16x8*)(Bl + fo);
        }
    };

    set_tap(0);
    load_frags(0, 0);

    for (int tap = 0; tap < 27; ++tap) {
        #pragma unroll
        for (int kc = 0; kc < KC; ++kc) {
            const int cur = kc & 1, nxt = cur ^ 1;
            if (kc + 1 < KC) {
                load_frags(nxt, kc + 1);
            } else {
                set_tap(tap < 26 ? tap + 1 : 26);
                load_frags(nxt, 0);
            }
            #pragma unroll
            for (int mt = 0; mt < MT; ++mt)
            #pragma unroll
            for (int nt = 0; nt < NT; ++nt) {
                acc[mt][nt] = __builtin_amdgcn_mfma_f32_16x16x32_bf16(fah[cur][mt], fbh[cur][nt], acc[mt][nt], 0, 0, 0);
                acc[mt][nt] = __builtin_amdgcn_mfma_f32_16x16x32_bf16(fah[cur][mt], fbl[cur][nt], acc[mt][nt], 0, 0, 0);
                acc[mt][nt] = __builtin_amdgcn_mfma_f32_16x16x32_bf16(fal[cur][mt], fbh[cur][nt], acc[mt][nt], 0, 0, 0);
            }
        }
    }

    #pragma unroll
    for (int mt = 0; mt < MT; ++mt) {
        const int vox0 = M0 + mt * 16 + kq * 4;
        #pragma unroll
        for (int nt = 0; nt < NT; ++nt) {
            const int co = (N0t + nt) * 16 + ml;
            #pragma unroll
            for (int r = 0; r < 4; ++r) {
                float v = acc[mt][nt][r];
                if (RELU) v = fmaxf(v, 0.f);
                const size_t yo = (size_t)(vox0 + r) * Cout + co;
                split_store(v, Yh + yo, Yl + yo);
            }
        }
    }
}

// ---------- stride-1 conv with LDS-staged A (for the big D=32 layer) (R8, VST=72) ------
template<int D, int R, bool RELU>
__global__ __launch_bounds__(256) void conv_s1_lds(
    const u16* __restrict__ Ah, const u16* __restrict__ Al,
    const u16* __restrict__ Bh, const u16* __restrict__ Bl,
    const float* __restrict__ bias,
    u16* __restrict__ Yh, u16* __restrict__ Yl)
{
    constexpr int KC  = 4;
    constexpr int SH  = R + 2;
    constexpr int SW  = D + 2;
    constexpr int VST = 72;
    __shared__ u16 sm[3 * SH * SW * VST];

    const int tid  = threadIdx.x;
    const int lane = tid & 63, widx = tid >> 6;
    const int ml = lane & 15, kq = lane >> 4;

    const int bpp = D / R;
    const int lb  = swz(blockIdx.x, gridDim.x);
    const int d   = lb / bpp;
    const int h0  = (lb % bpp) * R;
    const int N0  = widx * 2;

    f32x4 acc[4][2];
    #pragma unroll
    for (int nt = 0; nt < 2; ++nt) {
        const float bv = bias[(N0 + nt) * 16 + ml];
        #pragma unroll
        for (int mt = 0; mt < 4; ++mt) acc[mt][nt] = (f32x4){bv, bv, bv, bv};
    }

    for (int i = tid; i < 3 * SH * 2 * 9; i += 256) {
        const int slot = i / 9, c8 = i % 9;
        const int side = slot & 1, rr = slot >> 1;
        const int dd = rr / SH, hh = rr % SH;
        *(bf16x8*)(sm + ((dd * SH + hh) * SW + (side ? SW - 1 : 0)) * VST + c8 * 8) =
            (bf16x8){0,0,0,0,0,0,0,0};
    }

    bf16x8 cbh[2], cbl[2], nbh[2], nbl[2];
    auto loadB = [&](bf16x8 (&dh)[2], bf16x8 (&dl)[2], int kc, int tap) {
        #pragma unroll
        for (int nt = 0; nt < 2; ++nt) {
            const size_t fo = (((size_t)tap * 8 + N0 + nt) * KC + kc) * 512 + lane * 8;
            dh[nt] = *(const bf16x8*)(Bh + fo);
            dl[nt] = *(const bf16x8*)(Bl + fo);
        }
    };
    loadB(cbh, cbl, 0, 0);

    for (int kc = 0; kc < KC; ++kc) {
        __syncthreads();
        constexpr int NCH = 3 * SH * D * 8;
        for (int i = tid; i < NCH; i += 256) {
            const int vox = i >> 3, c8 = i & 7;
            const int ww = vox % D;
            const int rr = vox / D;
            const int hh = rr % SH, dd = rr / SH;
            const int pd = d + dd - 1, ph = h0 + hh - 1;
            u16* dst = sm + ((dd * SH + hh) * SW + ww + 1) * VST + c8 * 8;
            if ((unsigned)pd < (unsigned)D && (unsigned)ph < (unsigned)D) {
                const u16* srcb = (c8 < 4) ? Ah : Al;
                const size_t g = ((size_t)(pd * D + ph) * D + ww) * 128 + kc * 32 + (c8 & 3) * 8;
                *(bf16x8*)dst = *(const bf16x8*)(srcb + g);
            } else {
                *(bf16x8*)dst = (bf16x8){0,0,0,0,0,0,0,0};
            }
        }
        __syncthreads();

        for (int tap = 0; tap < 27; ++tap) {
            const int lin = kc * 27 + tap + 1;
            if (lin < KC * 27) loadB(nbh, nbl, lin / 27, lin % 27);
            const int kd = tap / 9, kh = (tap % 9) / 3, kw = tap % 3;
            bf16x8 fa_h[4], fa_l[4];
            #pragma unroll
            for (int mt = 0; mt < 4; ++mt) {
                const int m = mt * 16 + ml;
                const int mh = m / D, mw = m % D;
                const u16* p = sm + (((kd * SH) + (mh + kh)) * SW + (mw + kw)) * VST;
                fa_h[mt] = *(const bf16x8*)(p + kq * 8);
                fa_l[mt] = *(const bf16x8*)(p + 32 + kq * 8);
            }
            #pragma unroll
            for (int mt = 0; mt < 4; ++mt)
            #pragma unroll
            for (int nt = 0; nt < 2; ++nt) {
                acc[mt][nt] = __builtin_amdgcn_mfma_f32_16x16x32_bf16(fa_h[mt], cbh[nt], acc[mt][nt], 0, 0, 0);
                acc[mt][nt] = __builtin_amdgcn_mfma_f32_16x16x32_bf16(fa_h[mt], cbl[nt], acc[mt][nt], 0, 0, 0);
                acc[mt][nt] = __builtin_amdgcn_mfma_f32_16x16x32_bf16(fa_l[mt], cbh[nt], acc[mt][nt], 0, 0, 0);
            }
            #pragma unroll
            for (int nt = 0; nt < 2; ++nt) { cbh[nt] = nbh[nt]; cbl[nt] = nbl[nt]; }
        }
    }

    const size_t M0 = (size_t)(d * D + h0) * D;
    #pragma unroll
    for (int mt = 0; mt < 4; ++mt) {
        #pragma unroll
        for (int nt = 0; nt < 2; ++nt) {
            const int co = (N0 + nt) * 16 + ml;
            #pragma unroll
            for (int r = 0; r < 4; ++r) {
                float v = acc[mt][nt][r];
                if (RELU) v = fmaxf(v, 0.f);
                const size_t yo = (M0 + mt * 16 + kq * 4 + r) * 128 + co;
                split_store(v, Yh + yo, Yl + yo);
            }
        }
    }
}

// ---------- stride-2 MFMA deconv (parity-decomposed), register-double-buffered (R7) ----
// Still used for L0 (Din=8) and L2 (Din=16, Cout=128).
template<int CIN, int MT, int NT>
__global__ __launch_bounds__(64) void deconv_s2_mfma(
    const u16* __restrict__ Ah, const u16* __restrict__ Al,
    const u16* __restrict__ Bh, const u16* __restrict__ Bl,
    const float* __restrict__ bias, const u16* __restrict__ Z,
    u16* __restrict__ Yh, u16* __restrict__ Yl,
    int Din, int lD, int Cout, int nNtTot)
{
    constexpr int KC = CIN >> 5;
    const int Dout = 2 * Din;
    const int lane = threadIdx.x;
    const int ml = lane & 15, kq = lane >> 4;
    const int M0 = swz(blockIdx.x, gridDim.x) * (MT * 16);
    const int N0t = blockIdx.y * NT;
    const int par = blockIdx.z;
    const int rd = (par >> 2) & 1, rh = (par >> 1) & 1, rw = par & 1;

    int sw[MT], sh[MT], sd[MT];
    #pragma unroll
    for (int mt = 0; mt < MT; ++mt) {
        const int sv = M0 + mt * 16 + ml;
        sw[mt] = sv & (Din - 1); sh[mt] = (sv >> lD) & (Din - 1); sd[mt] = sv >> (2 * lD);
    }

    f32x4 acc[MT][NT];
    #pragma unroll
    for (int nt = 0; nt < NT; ++nt) {
        const float bv = bias[(N0t + nt) * 16 + ml];
        #pragma unroll
        for (int mt = 0; mt < MT; ++mt) acc[mt][nt] = (f32x4){bv, bv, bv, bv};
    }

    const int lw = rw ? 0 : 1, lh = rh ? 0 : 1, ld2 = rd ? 0 : 1;
    const int ntap = 1 << (lw + lh + ld2);

    const u16 *pah[MT], *pal[MT];
    size_t fb;
    auto set_tap = [&](int t) {
        const int tw_ = t & ((1 << lw) - 1);
        const int th_ = (t >> lw) & ((1 << lh) - 1);
        const int td_ = t >> (lw + lh);
        const int kd = rd ? 1 : (td_ ? 0 : 2);
        const int kh = rh ? 1 : (th_ ? 0 : 2);
        const int kw = rw ? 1 : (tw_ ? 0 : 2);
        const int dd = rd ? 0 : -td_, dh = rh ? 0 : -th_, dw = rw ? 0 : -tw_;
        const int tap = (kd * 3 + kh) * 3 + kw;
        #pragma unroll
        for (int mt = 0; mt < MT; ++mt) {
            const int id = sd[mt] + dd, ih = sh[mt] + dh, iw = sw[mt] + dw;
            const bool v = id >= 0 && ih >= 0 && iw >= 0;
            const size_t off = (size_t)((id * Din + ih) * Din + iw) * CIN;
            pah[mt] = v ? Ah + off : Z;
            pal[mt] = v ? Al + off : Z;
        }
        fb = ((size_t)tap * nNtTot + N0t) * KC;
    };

    bf16x8 fah[2][MT], fal[2][MT], fbh[2][NT], fbl[2][NT];
    auto load_frags = [&](int buf, int kc) {
        const int ko = kc * 32 + kq * 8;
        #pragma unroll
        for (int mt = 0; mt < MT; ++mt) {
            fah[buf][mt] = *(const bf16x8*)(pah[mt] + ko);
            fal[buf][mt] = *(const bf16x8*)(pal[mt] + ko);
        }
        #pragma unroll
        for (int nt = 0; nt < NT; ++nt) {
            const size_t fo = (fb + (size_t)nt * KC + kc) * 512 + lane * 8;
            fbh[buf][nt] = *(const bf16x8*)(Bh + fo);
            fbl[buf][nt] = *(const bf16x8*)(Bl + fo);
        }
    };

    set_tap(0);
    load_frags(0, 0);

    for (int t = 0; t < ntap; ++t) {
        #pragma unroll
        for (int kc = 0; kc < KC; ++kc) {
            const int cur = kc & 1, nxt = cur ^ 1;
            if (kc + 1 < KC) {
                load_frags(nxt, kc + 1);
            } else {
                set_tap(t + 1 < ntap ? t + 1 : t);
                load_frags(nxt, 0);
            }
            #pragma unroll
            for (int mt = 0; mt < MT; ++mt)
            #pragma unroll
            for (int nt = 0; nt < NT; ++nt) {
                acc[mt][nt] = __builtin_amdgcn_mfma_f32_16x16x32_bf16(fah[cur][mt], fbh[cur][nt], acc[mt][nt], 0, 0, 0);
                acc[mt][nt] = __builtin_amdgcn_mfma_f32_16x16x32_bf16(fah[cur][mt], fbl[cur][nt], acc[mt][nt], 0, 0, 0);
                acc[mt][nt] = __builtin_amdgcn_mfma_f32_16x16x32_bf16(fal[cur][mt], fbh[cur][nt], acc[mt][nt], 0, 0, 0);
            }
        }
    }

    #pragma unroll
    for (int mt = 0; mt < MT; ++mt) {
        #pragma unroll
        for (int r = 0; r < 4; ++r) {
            const int sv = M0 + mt * 16 + kq * 4 + r;
            const int svw = sv & (Din - 1), svh = (sv >> lD) & (Din - 1), svd = sv >> (2 * lD);
            const int od = 2 * svd + rd, oh = 2 * svh + rh, ow = 2 * svw + rw;
            const size_t yb = (size_t)((od * Dout + oh) * Dout + ow) * Cout;
            #pragma unroll
            for (int nt = 0; nt < NT; ++nt) {
                const int co = (N0t + nt) * 16 + ml;
                split_store(acc[mt][nt][r], Yh + yb + co, Yl + yb + co);
            }
        }
    }
}

// ---------- stride-2 deconv with LDS-staged A, all 4 parities of one rd-group ----------
// L4 only: Din=32, Cin=128, Cout=64 (NNT=4 granules). Block = 4 waves covers
// (d, h0..h0+1, all w) = 64 sub-voxels; wave widx owns the 16-voxel m-tile widx and ALL
// 4 cout granules. RD template = the rd parity bit: RD=0 needs planes {d-1,d}, 18 taps;
// RD=1 plane {d}, 9 taps. acc[4 parities][4 granules] = 64 VGPR. A read from LDS
// (2 b128/tap/wave); B ping-pong prefetched from global.
struct STap { int p2, dd, dh, dw, tap; };
template<int RD>
__device__ constexpr STap stap(int t) {
    int c = 0;
    for (int p2 = 0; p2 < 4; ++p2) {
        const int rh = p2 >> 1, rw = p2 & 1;
        for (int td = 0; td < (RD ? 1 : 2); ++td)
        for (int th = 0; th < (rh ? 1 : 2); ++th)
        for (int tw = 0; tw < (rw ? 1 : 2); ++tw) {
            if (c == t) {
                const int kd = RD ? 1 : (td ? 0 : 2);
                const int kh = rh ? 1 : (th ? 0 : 2);
                const int kw = rw ? 1 : (tw ? 0 : 2);
                return {p2, RD ? 0 : -td, rh ? 0 : -th, rw ? 0 : -tw, (kd * 3 + kh) * 3 + kw};
            }
            ++c;
        }
    }
    return {0, 0, 0, 0, 0};
}

template<int RD>
__global__ __launch_bounds__(256) void deconv_s2_lds(
    const u16* __restrict__ Ah, const u16* __restrict__ Al,
    const u16* __restrict__ Bh, const u16* __restrict__ Bl,
    const float* __restrict__ bias,
    u16* __restrict__ Yh, u16* __restrict__ Yl)
{
    constexpr int DIN = 32, KC = 4, NNT = 4, COUT = 64;
    constexpr int PD = RD ? 1 : 2;          // planes staged
    constexpr int SH = 3;                   // rows h0-1..h0+1
    constexpr int SW = DIN + 1;             // slots w-1..w  (slot 0 = left pad)
    constexpr int VST = 72;                 // 32 hi + 32 lo + 8 pad (16B-aligned)
    constexpr int G = RD ? 9 : 18;          // taps in this rd-group
    __shared__ u16 sm[PD * SH * SW * VST];

    const int tid  = threadIdx.x;
    const int lane = tid & 63, widx = tid >> 6;
    const int ml = lane & 15, kq = lane >> 4;

    const int lb = swz(blockIdx.x, gridDim.x);   // 512 blocks: d = lb>>4, hgrp = lb&15
    const int d  = lb >> 4;
    const int h0 = (lb & 15) * 2;

    // wave's m-tile: voxels v = widx*16 + ml ; mh = v>>5 in {0,1}, mw = v&31
    const int mh = widx >> 1;
    const int mw = (widx & 1) * 16 + ml;

    f32x4 acc[4][NNT];
    #pragma unroll
    for (int nt = 0; nt < NNT; ++nt) {
        const float bv = bias[nt * 16 + ml];
        #pragma unroll
        for (int p = 0; p < 4; ++p) acc[p][nt] = (f32x4){bv, bv, bv, bv};
    }

    // zero left-pad slots (slot 0 of every plane/row), first 64 u16 each
    if (tid < PD * SH * 8) {
        const int slot = tid >> 3, c8 = tid & 7;
        *(bf16x8*)(sm + slot * (SW * VST) + c8 * 8) = (bf16x8){0,0,0,0,0,0,0,0};
    }

    bf16x8 cb[NNT][2], nb[NNT][2];
    auto loadB = [&](bf16x8 (&dst)[NNT][2], int tap, int kc) {
        #pragma unroll
        for (int nt = 0; nt < NNT; ++nt) {
            const size_t fo = (((size_t)tap * NNT + nt) * KC + kc) * 512 + lane * 8;
            dst[nt][0] = *(const bf16x8*)(Bh + fo);
            dst[nt][1] = *(const bf16x8*)(Bl + fo);
        }
    };
    loadB(cb, stap<RD>(0).tap, 0);

    for (int kc = 0; kc < KC; ++kc) {
        __syncthreads();
        // stage PD x SH x DIN voxels x 8 chunks (4 hi + 4 lo)
        constexpr int NCH = PD * SH * DIN * 8;
        #pragma unroll
        for (int it = 0; it < NCH / 256; ++it) {
            const int i = tid + it * 256;
            const int vox = i >> 3, c8 = i & 7;
            const int ww = vox % DIN;
            const int rr = vox / DIN;
            const int hh = rr % SH, dd = rr / SH;     // dd in [0,PD)
            const int pd = d - (PD - 1) + dd;         // global plane
            const int ph = h0 - 1 + hh;               // global row
            u16* dst = sm + ((dd * SH + hh) * SW + ww + 1) * VST
                     + (c8 < 4 ? c8 * 8 : 32 + (c8 - 4) * 8);
            if (pd >= 0 && ph >= 0) {
                const u16* srcb = (c8 < 4) ? Ah : Al;
                const size_t g = ((size_t)(pd * DIN + ph) * DIN + ww) * 128
                               + kc * 32 + (c8 & 3) * 8;
                *(bf16x8*)dst = *(const bf16x8*)(srcb + g);
            } else {
                *(bf16x8*)dst = (bf16x8){0,0,0,0,0,0,0,0};
            }
        }
        __syncthreads();

        #pragma unroll
        for (int t = 0; t < G; ++t) {
            {   // prefetch next B (linear over kc*G, clamped at end)
                int lin = kc * G + t + 1;
                if (lin > KC * G - 1) lin = KC * G - 1;
                loadB(nb, stap<RD>(lin % G).tap, lin / G);
            }
            constexpr STap s = stap<RD>(0);  // dummy to appease some compilers
            (void)s;
            const STap ti = stap<RD>(t);     // constexpr-foldable under unroll
            const int plane = (PD - 1) + ti.dd;          // dd=0 -> last plane
            const int row   = mh + ti.dh + 1;
            const int slot  = mw + ti.dw + 1;
            const u16* p = sm + ((plane * SH + row) * SW + slot) * VST;
            const bf16x8 ahf = *(const bf16x8*)(p + kq * 8);
            const bf16x8 alf = *(const bf16x8*)(p + 32 + kq * 8);
            #pragma unroll
            for (int nt = 0; nt < NNT; ++nt) {
                acc[ti.p2][nt] = __builtin_amdgcn_mfma_f32_16x16x32_bf16(ahf, cb[nt][0], acc[ti.p2][nt], 0, 0, 0);
                acc[ti.p2][nt] = __builtin_amdgcn_mfma_f32_16x16x32_bf16(ahf, cb[nt][1], acc[ti.p2][nt], 0, 0, 0);
                acc[ti.p2][nt] = __builtin_amdgcn_mfma_f32_16x16x32_bf16(alf, cb[nt][0], acc[ti.p2][nt], 0, 0, 0);
            }
            #pragma unroll
            for (int nt = 0; nt < NNT; ++nt) { cb[nt][0] = nb[nt][0]; cb[nt][1] = nb[nt][1]; }
        }
    }

    // epilogue: outputs for 4 parities x 16 vox x 64 couts
    #pragma unroll
    for (int p2 = 0; p2 < 4; ++p2) {
        const int rh = p2 >> 1, rw = p2 & 1;
        #pragma unroll
        for (int r = 0; r < 4; ++r) {
            const int v  = widx * 16 + kq * 4 + r;       // out sub-voxel
            const int oh = 2 * (h0 + (v >> 5)) + rh;
            const int ow = 2 * (v & 31) + rw;
            const int od = 2 * d + RD;
            const size_t yb = (size_t)((od * 64 + oh) * 64 + ow) * COUT;
            #pragma unroll
            for (int nt = 0; nt < NNT; ++nt) {
                const int co = nt * 16 + ml;
                split_store(acc[p2][nt][r], Yh + yb + co, Yl + yb + co);
            }
        }
    }
}

// ---------- final layer: D=64, Cin=64 -> Cout=3 (N pad 16), hi+lo LDS (R9, VST=72) -----
#define L5_VST 72
#define L5_RST (66 * L5_VST)
__global__ __launch_bounds__(256) void conv_c3_lds(
    const u16* __restrict__ Ah, const u16* __restrict__ Al,
    const u16* __restrict__ Bh, const u16* __restrict__ Bl,
    const float* __restrict__ bias, float* __restrict__ out)
{
    __shared__ u16 sm[6 * L5_RST];

    const int tid  = threadIdx.x;
    const int lane = tid & 63, widx = tid >> 6;
    const int ml = lane & 15, kq = lane >> 4;

    const int lb = swz(blockIdx.x, gridDim.x);
    const int d  = lb >> 4;
    const int h0 = (lb & 15) * 4;

    const float bv = (ml < 3) ? bias[ml] : 0.f;
    f32x4 acc[4];
    #pragma unroll
    for (int mt = 0; mt < 4; ++mt) acc[mt] = (f32x4){bv, bv, bv, bv};

    bf16x8 cbh, cbl, nbh, nbl;
    auto loadB = [&](bf16x8& dh, bf16x8& dl, int tap, int kc) {
        const size_t fo = ((size_t)tap * 2 + kc) * 512 + lane * 8;
        dh = *(const bf16x8*)(Bh + fo);
        dl = *(const bf16x8*)(Bl + fo);
    };
    loadB(cbh, cbl, 0, 0);

    for (int kd = 0; kd < 3; ++kd) {
        const int pd = d + kd - 1;
        const bool vpd = (unsigned)pd < 64u;
        for (int kc = 0; kc < 2; ++kc) {
            __syncthreads();
            #pragma unroll
            for (int i = 0; i < 12; ++i) {
                const int c = tid + 256 * i;
                const int r = c >> 9;
                const int rem = c & 511;
                const int vox = rem >> 3, c8 = rem & 7;
                const int hh = h0 - 1 + r;
                u16* dst = sm + r * L5_RST + (vox + 1) * L5_VST
                         + (c8 < 4 ? c8 * 8 : 32 + (c8 - 4) * 8);
                if (vpd && (unsigned)hh < 64u) {
                    const u16* base = (c8 < 4) ? Ah : Al;
                    const size_t g = (size_t)((pd * 64 + hh) * 64 + vox) * 64
                                   + kc * 32 + (c8 & 3) * 8;
                    *(bf16x8*)dst = *(const bf16x8*)(base + g);
                } else {
                    *(bf16x8*)dst = (bf16x8){0,0,0,0,0,0,0,0};
                }
            }
            if (tid < 96) {
                const int r = tid >> 4, side = (tid >> 3) & 1, c8 = tid & 7;
                *(bf16x8*)(sm + r * L5_RST + (side ? 65 : 0) * L5_VST + c8 * 8) =
                    (bf16x8){0,0,0,0,0,0,0,0};
            }
            __syncthreads();

            #pragma unroll
            for (int t = 0; t < 9; ++t) {
                {
                    int lin = (kd * 2 + kc) * 9 + t + 1;
                    if (lin > 53) lin = 53;
                    const int Pn = lin / 9, tn = lin - Pn * 9;
                    loadB(nbh, nbl, (Pn >> 1) * 9 + tn, Pn & 1);
                }
                const int kh = t / 3, kw = t - kh * 3;
                const int slot = widx + kh;
                #pragma unroll
                for (int mt = 0; mt < 4; ++mt) {
                    const u16* p = sm + slot * L5_RST + (mt * 16 + ml + kw) * L5_VST;
                    const bf16x8 ahf = *(const bf16x8*)(p + kq * 8);
                    const bf16x8 alf = *(const bf16x8*)(p + 32 + kq * 8);
                    acc[mt] = __builtin_amdgcn_mfma_f32_16x16x32_bf16(ahf, cbh, acc[mt], 0, 0, 0);
                    acc[mt] = __builtin_amdgcn_mfma_f32_16x16x32_bf16(ahf, cbl, acc[mt], 0, 0, 0);
                    acc[mt] = __builtin_amdgcn_mfma_f32_16x16x32_bf16(alf, cbh, acc[mt], 0, 0, 0);
                }
                cbh = nbh; cbl = nbl;
            }
        }
    }

    if (ml < 3) {
        const int h = h0 + widx;
        const size_t vb = (size_t)(d * 64 + h) * 64;
        #pragma unroll
        for (int mt = 0; mt < 4; ++mt)
        #pragma unroll
        for (int r = 0; r < 4; ++r)
            out[(vb + mt * 16 + kq * 4 + r) * 3 + ml] = acc[mt][r];
    }
}

extern "C" void kernel_launch(void* const* d_in, const int* in_sizes, int n_in,
                              void* d_out, int out_size, void* d_ws, size_t ws_size,
                              hipStream_t stream)
{
    const float* x   = (const float*)d_in[0];
    const float* w0  = (const float*)d_in[1];  const float* b0  = (const float*)d_in[2];
    const float* w00 = (const float*)d_in[3];  const float* b00 = (const float*)d_in[4];
    const float* w1  = (const float*)d_in[5];  const float* b1  = (const float*)d_in[6];
    const float* w10 = (const float*)d_in[7];  const float* b10 = (const float*)d_in[8];
    const float* w2  = (const float*)d_in[9];  const float* b2  = (const float*)d_in[10];
    const float* w20 = (const float*)d_in[11]; const float* b20 = (const float*)d_in[12];
    float* out = (float*)d_out;

    char* ws = (char*)d_ws;
    float* zf = (float*)ws;
    u16*   Z  = (u16*)ws;
    u16* S4h = (u16*)(ws + 4096);
    u16* S4l = S4h + 221184;
    u16* S5h = S4l + 221184;
    u16* S5l = S5h + 27648;
    u16* Qh  = (u16*)(ws + 1048576);
    u16* Ql  = Qh + 4194304;
    u16* Ph  = (u16*)(ws + 17825792);
    u16* Pl  = Ph + 16777216;
    u16* S1h = (u16*)(ws + 60817408);
    u16* S1l = S1h + 442368;
    u16* S2h = S1l + 442368;
    u16* S2l = S2h + 442368;
    u16* S3h = S2l + 442368;
    u16* S3l = S3h + 442368;
    u16* S0h = S3l + 442368;
    u16* S0l = S0h + 442368;
    u16* Xh  = S0l + 442368;
    u16* Xl  = Xh + 65536;

    zero4k<<<1, 256, 0, stream>>>(zf);
    pack_all<<<dim3(216, 6), 256, 0, stream>>>(w0, w00, w1, w10, w2, w20,
        S0h, S0l, S1h, S1l, S2h, S2l, S3h, S3l, S4h, S4l, S5h, S5l);
    split_x<<<dim3(64), 256, 0, stream>>>(x, Xh, Xl);

    // L0: X(8^3x128) --s2 MFMA--> P(16^3x128). Din=8, MT=2,NT=4.
    deconv_s2_mfma<128, 2, 4><<<dim3(16, 2, 8), 64, 0, stream>>>(
        Xh, Xl, S0h, S0l, b0, Z, Ph, Pl, 8, 3, 128, 8);

    // L1: P --s1+relu--> Q (D=16). MT=1,NT=2.
    conv_s1_mfma<128, 1, 2, true><<<dim3(256, 4), 64, 0, stream>>>(
        Ph, Pl, S1h, S1l, b00, Z, Qh, Ql, 16, 4, 128, 8);

    // L2: Q --s2--> P (Din=16). MT=2,NT=4.
    deconv_s2_mfma<128, 2, 4><<<dim3(128, 2, 8), 64, 0, stream>>>(
        Qh, Ql, S2h, S2l, b1, Z, Ph, Pl, 16, 4, 128, 8);

    // L3: P --s1+relu--> Q (D=32). LDS-staged A, 512 blocks x 4 waves.
    conv_s1_lds<32, 2, true><<<dim3(512), 256, 0, stream>>>(
        Ph, Pl, S3h, S3l, b10, Qh, Ql);

    // L4: Q --s2--> P (Din=32, Cout=64). LDS-staged all-parity, rd-split: 2 launches.
    deconv_s2_lds<0><<<dim3(512), 256, 0, stream>>>(Qh, Ql, S4h, S4l, b2, Ph, Pl);
    deconv_s2_lds<1><<<dim3(512), 256, 0, stream>>>(Qh, Ql, S4h, S4l, b2, Ph, Pl);

    // L5: P --s1--> out (D=64, Cin=64, Cout=3 pad 16). hi+lo LDS-staged, 1024 blocks.
    conv_c3_lds<<<dim3(1024), 256, 0, stream>>>(Ph, Pl, S5h, S5l, b20, out);
}

// Round 13
// 406.323 us; speedup vs baseline: 1.0908x; 1.0908x over previous
//
#include <hip/hip_runtime.h>

// Decoder via bf16 hi/lo-split MFMA implicit GEMM.
//   fp32 v = hi(bf16) + lo(bf16);  A*B ~= Ah*Bh + Ah*Bl + Al*Bh  (3x mfma_f32_16x16x32_bf16)
// conv_transpose SAME:
//   stride1: O[o] = sum_k W[k] X[o+k-1]
//   stride2, parity r: r==1 -> tap kd=1,id=i ; r==0 -> kd=2,id=i and kd=0,id=i-1  (o=2i+r)
// Weights DHWIO [tap][ci][co], activations NDHWC, hi/lo separate arrays.
// MFMA layouts (verified): A[m=lane&15][k=(lane>>4)*8+j], B[n=lane&15][k=(lane>>4)*8+j],
// D: col=lane&15, row=(lane>>4)*4+reg.
// LDS rule (R10): voxel slot stride must be a multiple of 8 u16 (16B) or b128 LDS ops split.
// R12 lesson: LDS-staging L4's stride-2 (rd-split, 4-granule) is below break-even —
// staging:compute ratio worse than the 1-wave streaming kernel at 4 waves/SIMD. Reverted.
//
// Round13: L4 back to R11's deconv_s2_mfma<128,4,4> (known-good 407us config) +
// zero4k/split_x folded into pack_all (3 launches -> 1 at the front of the chain).

typedef __attribute__((ext_vector_type(8))) short bf16x8;
typedef __attribute__((ext_vector_type(4))) float f32x4;
typedef unsigned short u16;

__device__ __forceinline__ u16 f2bf(float f) {
    unsigned u = __builtin_bit_cast(unsigned, f);
    u += 0x7fffu + ((u >> 16) & 1u);
    return (u16)(u >> 16);
}
__device__ __forceinline__ float bf2f(u16 h) {
    unsigned u = ((unsigned)h) << 16;
    return __builtin_bit_cast(float, u);
}
__device__ __forceinline__ void split_store(float v, u16* ph, u16* pl) {
    u16 h = f2bf(v);
    *ph = h;
    *pl = f2bf(v - bf2f(h));
}
__device__ __forceinline__ int rfl(int v) { return __builtin_amdgcn_readfirstlane(v); }
__device__ __forceinline__ int swz(int bx, int G) { return (bx & 7) * (G >> 3) + (bx >> 3); }

// pack fp32 w[27][Cin][Cout] -> bf16 hi/lo frags, layout [tap][nt][kc][lane][8].
// blockIdx.y = layer 0..5; y==6: split x into Xh/Xl (+zero page at blockIdx.x==64).
__global__ __launch_bounds__(256) void pack_all(
    const float* __restrict__ x, float* __restrict__ zf,
    u16* __restrict__ Xh, u16* __restrict__ Xl,
    const float* __restrict__ w0_, const float* __restrict__ w1_,
    const float* __restrict__ w2_, const float* __restrict__ w3_,
    const float* __restrict__ w4_, const float* __restrict__ w5_,
    u16* s0h, u16* s0l, u16* s1h, u16* s1l, u16* s2h, u16* s2l,
    u16* s3h, u16* s3l, u16* s4h, u16* s4l, u16* s5h, u16* s5l)
{
    if (blockIdx.y == 6) {
        if (blockIdx.x < 64) {
            const int i = (blockIdx.x * 256 + threadIdx.x) * 4;
            const float4 v = *(const float4*)(x + i);
            split_store(v.x, Xh + i,     Xl + i);
            split_store(v.y, Xh + i + 1, Xl + i + 1);
            split_store(v.z, Xh + i + 2, Xl + i + 2);
            split_store(v.w, Xh + i + 3, Xl + i + 3);
        } else if (blockIdx.x == 64) {
            ((float4*)zf)[threadIdx.x] = make_float4(0.f, 0.f, 0.f, 0.f);
        }
        return;
    }
    const float* w; u16 *bh, *bl; int Cin, Cout, nNt;
    switch (blockIdx.y) {
        case 0: w = w0_; bh = s0h; bl = s0l; Cin = 128; Cout = 128; nNt = 8; break;
        case 1: w = w1_; bh = s1h; bl = s1l; Cin = 128; Cout = 128; nNt = 8; break;
        case 2: w = w2_; bh = s2h; bl = s2l; Cin = 128; Cout = 128; nNt = 8; break;
        case 3: w = w3_; bh = s3h; bl = s3l; Cin = 128; Cout = 128; nNt = 8; break;
        case 4: w = w4_; bh = s4h; bl = s4l; Cin = 128; Cout = 64;  nNt = 4; break;
        default:w = w5_; bh = s5h; bl = s5l; Cin = 64;  Cout = 3;   nNt = 1; break;
    }
    const int KC = Cin >> 5;
    const int total = 27 * nNt * KC * 64;
    int t = blockIdx.x * 256 + threadIdx.x;
    if (t >= total) return;
    const int lane = t & 63;
    int r = t >> 6;
    const int kc = r % KC; r /= KC;
    const int nt = r % nNt; r /= nNt;
    const int tap = r;
    const int n  = nt * 16 + (lane & 15);
    const int k0 = kc * 32 + (lane >> 4) * 8;
    const size_t o = (size_t)t * 8;
    for (int j = 0; j < 8; ++j) {
        float v = (n < Cout) ? w[((size_t)tap * Cin + k0 + j) * Cout + n] : 0.f;
        u16 h = f2bf(v);
        bh[o + j] = h;
        bl[o + j] = f2bf(v - bf2f(h));
    }
}

// ---------- stride-1 MFMA conv, register-double-buffered K-loop (R7) ----------
template<int CIN, int MT, int NT, bool RELU>
__global__ __launch_bounds__(64) void conv_s1_mfma(
    const u16* __restrict__ Ah, const u16* __restrict__ Al,
    const u16* __restrict__ Bh, const u16* __restrict__ Bl,
    const float* __restrict__ bias, const u16* __restrict__ Z,
    u16* __restrict__ Yh, u16* __restrict__ Yl,
    int D, int lD, int Cout, int nNtTot)
{
    constexpr int KC = CIN >> 5;
    const int lane = threadIdx.x;
    const int ml = lane & 15, kq = lane >> 4;
    const int M0 = swz(blockIdx.x, gridDim.x) * (MT * 16);
    const int N0t = blockIdx.y * NT;

    int vw[MT], vh[MT], vd[MT];
    #pragma unroll
    for (int mt = 0; mt < MT; ++mt) {
        const int vox = M0 + mt * 16 + ml;
        vw[mt] = vox & (D - 1); vh[mt] = (vox >> lD) & (D - 1); vd[mt] = vox >> (2 * lD);
    }

    f32x4 acc[MT][NT];
    #pragma unroll
    for (int nt = 0; nt < NT; ++nt) {
        const float bv = bias[(N0t + nt) * 16 + ml];
        #pragma unroll
        for (int mt = 0; mt < MT; ++mt) acc[mt][nt] = (f32x4){bv, bv, bv, bv};
    }

    const u16 *pah[MT], *pal[MT];
    size_t fb;
    auto set_tap = [&](int tap) {
        const int kd = tap / 9, kh = (tap % 9) / 3, kw = tap % 3;
        #pragma unroll
        for (int mt = 0; mt < MT; ++mt) {
            const int id = vd[mt] + kd - 1, ih = vh[mt] + kh - 1, iw = vw[mt] + kw - 1;
            const bool v = (unsigned)id < (unsigned)D && (unsigned)ih < (unsigned)D &&
                           (unsigned)iw < (unsigned)D;
            const size_t off = (size_t)((id * D + ih) * D + iw) * CIN;
            pah[mt] = v ? Ah + off : Z;
            pal[mt] = v ? Al + off : Z;
        }
        fb = ((size_t)tap * nNtTot + N0t) * KC;
    };

    bf16x8 fah[2][MT], fal[2][MT], fbh[2][NT], fbl[2][NT];
    auto load_frags = [&](int buf, int kc) {
        const int ko = kc * 32 + kq * 8;
        #pragma unroll
        for (int mt = 0; mt < MT; ++mt) {
            fah[buf][mt] = *(const bf16x8*)(pah[mt] + ko);
            fal[buf][mt] = *(const bf16x8*)(pal[mt] + ko);
        }
        #pragma unroll
        for (int nt = 0; nt < NT; ++nt) {
            const size_t fo = (fb + (size_t)nt * KC + kc) * 512 + lane * 8;
            fbh[buf][nt] = *(const bf16x8*)(Bh + fo);
            fbl[buf][nt] = *(const bf16x8*)(Bl + fo);
        }
    };

    set_tap(0);
    load_frags(0, 0);

    for (int tap = 0; tap < 27; ++tap) {
        #pragma unroll
        for (int kc = 0; kc < KC; ++kc) {
            const int cur = kc & 1, nxt = cur ^ 1;
            if (kc + 1 < KC) {
                load_frags(nxt, kc + 1);
            } else {
                set_tap(tap < 26 ? tap + 1 : 26);
                load_frags(nxt, 0);
            }
            #pragma unroll
            for (int mt = 0; mt < MT; ++mt)
            #pragma unroll
            for (int nt = 0; nt < NT; ++nt) {
                acc[mt][nt] = __builtin_amdgcn_mfma_f32_16x16x32_bf16(fah[cur][mt], fbh[cur][nt], acc[mt][nt], 0, 0, 0);
                acc[mt][nt] = __builtin_amdgcn_mfma_f32_16x16x32_bf16(fah[cur][mt], fbl[cur][nt], acc[mt][nt], 0, 0, 0);
                acc[mt][nt] = __builtin_amdgcn_mfma_f32_16x16x32_bf16(fal[cur][mt], fbh[cur][nt], acc[mt][nt], 0, 0, 0);
            }
        }
    }

    #pragma unroll
    for (int mt = 0; mt < MT; ++mt) {
        const int vox0 = M0 + mt * 16 + kq * 4;
        #pragma unroll
        for (int nt = 0; nt < NT; ++nt) {
            const int co = (N0t + nt) * 16 + ml;
            #pragma unroll
            for (int r = 0; r < 4; ++r) {
                float v = acc[mt][nt][r];
                if (RELU) v = fmaxf(v, 0.f);
                const size_t yo = (size_t)(vox0 + r) * Cout + co;
                split_store(v, Yh + yo, Yl + yo);
            }
        }
    }
}

// ---------- stride-1 conv with LDS-staged A (for the big D=32 layer) (R8, VST=72) ------
template<int D, int R, bool RELU>
__global__ __launch_bounds__(256) void conv_s1_lds(
    const u16* __restrict__ Ah, const u16* __restrict__ Al,
    const u16* __restrict__ Bh, const u16* __restrict__ Bl,
    const float* __restrict__ bias,
    u16* __restrict__ Yh, u16* __restrict__ Yl)
{
    constexpr int KC  = 4;
    constexpr int SH  = R + 2;
    constexpr int SW  = D + 2;
    constexpr int VST = 72;
    __shared__ u16 sm[3 * SH * SW * VST];

    const int tid  = threadIdx.x;
    const int lane = tid & 63, widx = tid >> 6;
    const int ml = lane & 15, kq = lane >> 4;

    const int bpp = D / R;
    const int lb  = swz(blockIdx.x, gridDim.x);
    const int d   = lb / bpp;
    const int h0  = (lb % bpp) * R;
    const int N0  = widx * 2;

    f32x4 acc[4][2];
    #pragma unroll
    for (int nt = 0; nt < 2; ++nt) {
        const float bv = bias[(N0 + nt) * 16 + ml];
        #pragma unroll
        for (int mt = 0; mt < 4; ++mt) acc[mt][nt] = (f32x4){bv, bv, bv, bv};
    }

    for (int i = tid; i < 3 * SH * 2 * 9; i += 256) {
        const int slot = i / 9, c8 = i % 9;
        const int side = slot & 1, rr = slot >> 1;
        const int dd = rr / SH, hh = rr % SH;
        *(bf16x8*)(sm + ((dd * SH + hh) * SW + (side ? SW - 1 : 0)) * VST + c8 * 8) =
            (bf16x8){0,0,0,0,0,0,0,0};
    }

    bf16x8 cbh[2], cbl[2], nbh[2], nbl[2];
    auto loadB = [&](bf16x8 (&dh)[2], bf16x8 (&dl)[2], int kc, int tap) {
        #pragma unroll
        for (int nt = 0; nt < 2; ++nt) {
            const size_t fo = (((size_t)tap * 8 + N0 + nt) * KC + kc) * 512 + lane * 8;
            dh[nt] = *(const bf16x8*)(Bh + fo);
            dl[nt] = *(const bf16x8*)(Bl + fo);
        }
    };
    loadB(cbh, cbl, 0, 0);

    for (int kc = 0; kc < KC; ++kc) {
        __syncthreads();
        constexpr int NCH = 3 * SH * D * 8;
        for (int i = tid; i < NCH; i += 256) {
            const int vox = i >> 3, c8 = i & 7;
            const int ww = vox % D;
            const int rr = vox / D;
            const int hh = rr % SH, dd = rr / SH;
            const int pd = d + dd - 1, ph = h0 + hh - 1;
            u16* dst = sm + ((dd * SH + hh) * SW + ww + 1) * VST + c8 * 8;
            if ((unsigned)pd < (unsigned)D && (unsigned)ph < (unsigned)D) {
                const u16* srcb = (c8 < 4) ? Ah : Al;
                const size_t g = ((size_t)(pd * D + ph) * D + ww) * 128 + kc * 32 + (c8 & 3) * 8;
                *(bf16x8*)dst = *(const bf16x8*)(srcb + g);
            } else {
                *(bf16x8*)dst = (bf16x8){0,0,0,0,0,0,0,0};
            }
        }
        __syncthreads();

        for (int tap = 0; tap < 27; ++tap) {
            const int lin = kc * 27 + tap + 1;
            if (lin < KC * 27) loadB(nbh, nbl, lin / 27, lin % 27);
            const int kd = tap / 9, kh = (tap % 9) / 3, kw = tap % 3;
            bf16x8 fa_h[4], fa_l[4];
            #pragma unroll
            for (int mt = 0; mt < 4; ++mt) {
                const int m = mt * 16 + ml;
                const int mh = m / D, mw = m % D;
                const u16* p = sm + (((kd * SH) + (mh + kh)) * SW + (mw + kw)) * VST;
                fa_h[mt] = *(const bf16x8*)(p + kq * 8);
                fa_l[mt] = *(const bf16x8*)(p + 32 + kq * 8);
            }
            #pragma unroll
            for (int mt = 0; mt < 4; ++mt)
            #pragma unroll
            for (int nt = 0; nt < 2; ++nt) {
                acc[mt][nt] = __builtin_amdgcn_mfma_f32_16x16x32_bf16(fa_h[mt], cbh[nt], acc[mt][nt], 0, 0, 0);
                acc[mt][nt] = __builtin_amdgcn_mfma_f32_16x16x32_bf16(fa_h[mt], cbl[nt], acc[mt][nt], 0, 0, 0);
                acc[mt][nt] = __builtin_amdgcn_mfma_f32_16x16x32_bf16(fa_l[mt], cbh[nt], acc[mt][nt], 0, 0, 0);
            }
            #pragma unroll
            for (int nt = 0; nt < 2; ++nt) { cbh[nt] = nbh[nt]; cbl[nt] = nbl[nt]; }
        }
    }

    const size_t M0 = (size_t)(d * D + h0) * D;
    #pragma unroll
    for (int mt = 0; mt < 4; ++mt) {
        #pragma unroll
        for (int nt = 0; nt < 2; ++nt) {
            const int co = (N0 + nt) * 16 + ml;
            #pragma unroll
            for (int r = 0; r < 4; ++r) {
                float v = acc[mt][nt][r];
                if (RELU) v = fmaxf(v, 0.f);
                const size_t yo = (M0 + mt * 16 + kq * 4 + r) * 128 + co;
                split_store(v, Yh + yo, Yl + yo);
            }
        }
    }
}

// ---------- stride-2 MFMA deconv (parity-decomposed), register-double-buffered (R7) ----
template<int CIN, int MT, int NT>
__global__ __launch_bounds__(64) void deconv_s2_mfma(
    const u16* __restrict__ Ah, const u16* __restrict__ Al,
    const u16* __restrict__ Bh, const u16* __restrict__ Bl,
    const float* __restrict__ bias, const u16* __restrict__ Z,
    u16* __restrict__ Yh, u16* __restrict__ Yl,
    int Din, int lD, int Cout, int nNtTot)
{
    constexpr int KC = CIN >> 5;
    const int Dout = 2 * Din;
    const int lane = threadIdx.x;
    const int ml = lane & 15, kq = lane >> 4;
    const int M0 = swz(blockIdx.x, gridDim.x) * (MT * 16);
    const int N0t = blockIdx.y * NT;
    const int par = blockIdx.z;
    const int rd = (par >> 2) & 1, rh = (par >> 1) & 1, rw = par & 1;

    int sw[MT], sh[MT], sd[MT];
    #pragma unroll
    for (int mt = 0; mt < MT; ++mt) {
        const int sv = M0 + mt * 16 + ml;
        sw[mt] = sv & (Din - 1); sh[mt] = (sv >> lD) & (Din - 1); sd[mt] = sv >> (2 * lD);
    }

    f32x4 acc[MT][NT];
    #pragma unroll
    for (int nt = 0; nt < NT; ++nt) {
        const float bv = bias[(N0t + nt) * 16 + ml];
        #pragma unroll
        for (int mt = 0; mt < MT; ++mt) acc[mt][nt] = (f32x4){bv, bv, bv, bv};
    }

    const int lw = rw ? 0 : 1, lh = rh ? 0 : 1, ld2 = rd ? 0 : 1;
    const int ntap = 1 << (lw + lh + ld2);

    const u16 *pah[MT], *pal[MT];
    size_t fb;
    auto set_tap = [&](int t) {
        const int tw_ = t & ((1 << lw) - 1);
        const int th_ = (t >> lw) & ((1 << lh) - 1);
        const int td_ = t >> (lw + lh);
        const int kd = rd ? 1 : (td_ ? 0 : 2);
        const int kh = rh ? 1 : (th_ ? 0 : 2);
        const int kw = rw ? 1 : (tw_ ? 0 : 2);
        const int dd = rd ? 0 : -td_, dh = rh ? 0 : -th_, dw = rw ? 0 : -tw_;
        const int tap = (kd * 3 + kh) * 3 + kw;
        #pragma unroll
        for (int mt = 0; mt < MT; ++mt) {
            const int id = sd[mt] + dd, ih = sh[mt] + dh, iw = sw[mt] + dw;
            const bool v = id >= 0 && ih >= 0 && iw >= 0;
            const size_t off = (size_t)((id * Din + ih) * Din + iw) * CIN;
            pah[mt] = v ? Ah + off : Z;
            pal[mt] = v ? Al + off : Z;
        }
        fb = ((size_t)tap * nNtTot + N0t) * KC;
    };

    bf16x8 fah[2][MT], fal[2][MT], fbh[2][NT], fbl[2][NT];
    auto load_frags = [&](int buf, int kc) {
        const int ko = kc * 32 + kq * 8;
        #pragma unroll
        for (int mt = 0; mt < MT; ++mt) {
            fah[buf][mt] = *(const bf16x8*)(pah[mt] + ko);
            fal[buf][mt] = *(const bf16x8*)(pal[mt] + ko);
        }
        #pragma unroll
        for (int nt = 0; nt < NT; ++nt) {
            const size_t fo = (fb + (size_t)nt * KC + kc) * 512 + lane * 8;
            fbh[buf][nt] = *(const bf16x8*)(Bh + fo);
            fbl[buf][nt] = *(const bf16x8*)(Bl + fo);
        }
    };

    set_tap(0);
    load_frags(0, 0);

    for (int t = 0; t < ntap; ++t) {
        #pragma unroll
        for (int kc = 0; kc < KC; ++kc) {
            const int cur = kc & 1, nxt = cur ^ 1;
            if (kc + 1 < KC) {
                load_frags(nxt, kc + 1);
            } else {
                set_tap(t + 1 < ntap ? t + 1 : t);
                load_frags(nxt, 0);
            }
            #pragma unroll
            for (int mt = 0; mt < MT; ++mt)
            #pragma unroll
            for (int nt = 0; nt < NT; ++nt) {
                acc[mt][nt] = __builtin_amdgcn_mfma_f32_16x16x32_bf16(fah[cur][mt], fbh[cur][nt], acc[mt][nt], 0, 0, 0);
                acc[mt][nt] = __builtin_amdgcn_mfma_f32_16x16x32_bf16(fah[cur][mt], fbl[cur][nt], acc[mt][nt], 0, 0, 0);
                acc[mt][nt] = __builtin_amdgcn_mfma_f32_16x16x32_bf16(fal[cur][mt], fbh[cur][nt], acc[mt][nt], 0, 0, 0);
            }
        }
    }

    #pragma unroll
    for (int mt = 0; mt < MT; ++mt) {
        #pragma unroll
        for (int r = 0; r < 4; ++r) {
            const int sv = M0 + mt * 16 + kq * 4 + r;
            const int svw = sv & (Din - 1), svh = (sv >> lD) & (Din - 1), svd = sv >> (2 * lD);
            const int od = 2 * svd + rd, oh = 2 * svh + rh, ow = 2 * svw + rw;
            const size_t yb = (size_t)((od * Dout + oh) * Dout + ow) * Cout;
            #pragma unroll
            for (int nt = 0; nt < NT; ++nt) {
                const int co = (N0t + nt) * 16 + ml;
                split_store(acc[mt][nt][r], Yh + yb + co, Yl + yb + co);
            }
        }
    }
}

// ---------- final layer: D=64, Cin=64 -> Cout=3 (N pad 16), hi+lo LDS (R9, VST=72) -----
#define L5_VST 72
#define L5_RST (66 * L5_VST)
__global__ __launch_bounds__(256) void conv_c3_lds(
    const u16* __restrict__ Ah, const u16* __restrict__ Al,
    const u16* __restrict__ Bh, const u16* __restrict__ Bl,
    const float* __restrict__ bias, float* __restrict__ out)
{
    __shared__ u16 sm[6 * L5_RST];

    const int tid  = threadIdx.x;
    const int lane = tid & 63, widx = tid >> 6;
    const int ml = lane & 15, kq = lane >> 4;

    const int lb = swz(blockIdx.x, gridDim.x);
    const int d  = lb >> 4;
    const int h0 = (lb & 15) * 4;

    const float bv = (ml < 3) ? bias[ml] : 0.f;
    f32x4 acc[4];
    #pragma unroll
    for (int mt = 0; mt < 4; ++mt) acc[mt] = (f32x4){bv, bv, bv, bv};

    bf16x8 cbh, cbl, nbh, nbl;
    auto loadB = [&](bf16x8& dh, bf16x8& dl, int tap, int kc) {
        const size_t fo = ((size_t)tap * 2 + kc) * 512 + lane * 8;
        dh = *(const bf16x8*)(Bh + fo);
        dl = *(const bf16x8*)(Bl + fo);
    };
    loadB(cbh, cbl, 0, 0);

    for (int kd = 0; kd < 3; ++kd) {
        const int pd = d + kd - 1;
        const bool vpd = (unsigned)pd < 64u;
        for (int kc = 0; kc < 2; ++kc) {
            __syncthreads();
            #pragma unroll
            for (int i = 0; i < 12; ++i) {
                const int c = tid + 256 * i;
                const int r = c >> 9;
                const int rem = c & 511;
                const int vox = rem >> 3, c8 = rem & 7;
                const int hh = h0 - 1 + r;
                u16* dst = sm + r * L5_RST + (vox + 1) * L5_VST
                         + (c8 < 4 ? c8 * 8 : 32 + (c8 - 4) * 8);
                if (vpd && (unsigned)hh < 64u) {
                    const u16* base = (c8 < 4) ? Ah : Al;
                    const size_t g = (size_t)((pd * 64 + hh) * 64 + vox) * 64
                                   + kc * 32 + (c8 & 3) * 8;
                    *(bf16x8*)dst = *(const bf16x8*)(base + g);
                } else {
                    *(bf16x8*)dst = (bf16x8){0,0,0,0,0,0,0,0};
                }
            }
            if (tid < 96) {
                const int r = tid >> 4, side = (tid >> 3) & 1, c8 = tid & 7;
                *(bf16x8*)(sm + r * L5_RST + (side ? 65 : 0) * L5_VST + c8 * 8) =
                    (bf16x8){0,0,0,0,0,0,0,0};
            }
            __syncthreads();

            #pragma unroll
            for (int t = 0; t < 9; ++t) {
                {
                    int lin = (kd * 2 + kc) * 9 + t + 1;
                    if (lin > 53) lin = 53;
                    const int Pn = lin / 9, tn = lin - Pn * 9;
                    loadB(nbh, nbl, (Pn >> 1) * 9 + tn, Pn & 1);
                }
                const int kh = t / 3, kw = t - kh * 3;
                const int slot = widx + kh;
                #pragma unroll
                for (int mt = 0; mt < 4; ++mt) {
                    const u16* p = sm + slot * L5_RST + (mt * 16 + ml + kw) * L5_VST;
                    const bf16x8 ahf = *(const bf16x8*)(p + kq * 8);
                    const bf16x8 alf = *(const bf16x8*)(p + 32 + kq * 8);
                    acc[mt] = __builtin_amdgcn_mfma_f32_16x16x32_bf16(ahf, cbh, acc[mt], 0, 0, 0);
                    acc[mt] = __builtin_amdgcn_mfma_f32_16x16x32_bf16(ahf, cbl, acc[mt], 0, 0, 0);
                    acc[mt] = __builtin_amdgcn_mfma_f32_16x16x32_bf16(alf, cbh, acc[mt], 0, 0, 0);
                }
                cbh = nbh; cbl = nbl;
            }
        }
    }

    if (ml < 3) {
        const int h = h0 + widx;
        const size_t vb = (size_t)(d * 64 + h) * 64;
        #pragma unroll
        for (int mt = 0; mt < 4; ++mt)
        #pragma unroll
        for (int r = 0; r < 4; ++r)
            out[(vb + mt * 16 + kq * 4 + r) * 3 + ml] = acc[mt][r];
    }
}

extern "C" void kernel_launch(void* const* d_in, const int* in_sizes, int n_in,
                              void* d_out, int out_size, void* d_ws, size_t ws_size,
                              hipStream_t stream)
{
    const float* x   = (const float*)d_in[0];
    const float* w0  = (const float*)d_in[1];  const float* b0  = (const float*)d_in[2];
    const float* w00 = (const float*)d_in[3];  const float* b00 = (const float*)d_in[4];
    const float* w1  = (const float*)d_in[5];  const float* b1  = (const float*)d_in[6];
    const float* w10 = (const float*)d_in[7];  const float* b10 = (const float*)d_in[8];
    const float* w2  = (const float*)d_in[9];  const float* b2  = (const float*)d_in[10];
    const float* w20 = (const float*)d_in[11]; const float* b20 = (const float*)d_in[12];
    float* out = (float*)d_out;

    char* ws = (char*)d_ws;
    float* zf = (float*)ws;                      // 4 KB zero page
    u16*   Z  = (u16*)ws;
    u16* S4h = (u16*)(ws + 4096);                // durable packed weights (L4, L5)
    u16* S4l = S4h + 221184;
    u16* S5h = S4l + 221184;
    u16* S5l = S5h + 27648;
    u16* Qh  = (u16*)(ws + 1048576);             // 32^3 x 128
    u16* Ql  = Qh + 4194304;
    u16* Ph  = (u16*)(ws + 17825792);            // 64^3 x 64
    u16* Pl  = Ph + 16777216;
    // transient packed weights (L0..L3) + X in the Pl tail (clobbered only by L4 output)
    u16* S1h = (u16*)(ws + 60817408);
    u16* S1l = S1h + 442368;
    u16* S2h = S1l + 442368;
    u16* S2l = S2h + 442368;
    u16* S3h = S2l + 442368;
    u16* S3l = S3h + 442368;
    u16* S0h = S3l + 442368;
    u16* S0l = S0h + 442368;
    u16* Xh  = S0l + 442368;
    u16* Xl  = Xh + 65536;

    // pack weights for all 6 layers + split x + zero page, one launch
    pack_all<<<dim3(216, 7), 256, 0, stream>>>(x, zf, Xh, Xl,
        w0, w00, w1, w10, w2, w20,
        S0h, S0l, S1h, S1l, S2h, S2l, S3h, S3l, S4h, S4l, S5h, S5l);

    // L0: X(8^3x128) --s2 MFMA--> P(16^3x128). Din=8, MT=2,NT=4.
    deconv_s2_mfma<128, 2, 4><<<dim3(16, 2, 8), 64, 0, stream>>>(
        Xh, Xl, S0h, S0l, b0, Z, Ph, Pl, 8, 3, 128, 8);

    // L1: P --s1+relu--> Q (D=16). MT=1,NT=2.
    conv_s1_mfma<128, 1, 2, true><<<dim3(256, 4), 64, 0, stream>>>(
        Ph, Pl, S1h, S1l, b00, Z, Qh, Ql, 16, 4, 128, 8);

    // L2: Q --s2--> P (Din=16). MT=2,NT=4.
    deconv_s2_mfma<128, 2, 4><<<dim3(128, 2, 8), 64, 0, stream>>>(
        Qh, Ql, S2h, S2l, b1, Z, Ph, Pl, 16, 4, 128, 8);

    // L3: P --s1+relu--> Q (D=32). LDS-staged A, 512 blocks x 4 waves.
    conv_s1_lds<32, 2, true><<<dim3(512), 256, 0, stream>>>(
        Ph, Pl, S3h, S3l, b10, Qh, Ql);

    // L4: Q --s2--> P (Din=32, Cout=64). MT=4,NT=4 (R11 known-good).
    deconv_s2_mfma<128, 4, 4><<<dim3(512, 1, 8), 64, 0, stream>>>(
        Qh, Ql, S4h, S4l, b2, Z, Ph, Pl, 32, 5, 64, 4);

    // L5: P --s1--> out (D=64, Cin=64, Cout=3 pad 16). hi+lo LDS-staged, 1024 blocks.
    conv_c3_lds<<<dim3(1024), 256, 0, stream>>>(Ph, Pl, S5h, S5l, b20, out);
}

// Round 14
// 369.874 us; speedup vs baseline: 1.1983x; 1.0985x over previous
//
#include <hip/hip_runtime.h>

// Decoder via bf16 hi/lo-split MFMA implicit GEMM.
//   fp32 v = hi(bf16) + lo(bf16);  A*B ~= Ah*Bh + Ah*Bl + Al*Bh  (3x mfma_f32_16x16x32_bf16)
// conv_transpose SAME:
//   stride1: O[o] = sum_k W[k] X[o+k-1]
//   stride2, parity r: r==1 -> tap kd=1,id=i ; r==0 -> kd=2,id=i and kd=0,id=i-1  (o=2i+r)
// Weights DHWIO [tap][ci][co], activations NDHWC, hi/lo separate arrays.
// MFMA layouts (verified): A[m=lane&15][k=(lane>>4)*8+j], B[n=lane&15][k=(lane>>4)*8+j],
// D: col=lane&15, row=(lane>>4)*4+reg. C/D layout is dtype-independent.
// LDS rule (R10): voxel slot stride must be a multiple of 8 u16 (16B) or b128 LDS ops split.
//
// Round14: spend precision budget (absmax 4.9e-4 vs 2.2e-3 threshold) on the P->L5 edge,
// which feeds ONLY the final layer (no downstream amplification): L4 stores P as fp16
// SINGLE (write traffic halves), L5 runs fp16 A x fp16-hi/lo W (2 MFMA terms, weights
// exact to 2^-21, only activation-quantization error ~2.8e-4 RMS enters). L5 LDS slab
// halves (VST=40 u16, still 16B-aligned), staging+A-reads halve, MFMA 648->432 per block.

typedef __attribute__((ext_vector_type(8))) short bf16x8;
typedef __attribute__((ext_vector_type(8))) _Float16 f16x8;
typedef __attribute__((ext_vector_type(4))) float f32x4;
typedef unsigned short u16;

__device__ __forceinline__ u16 f2bf(float f) {
    unsigned u = __builtin_bit_cast(unsigned, f);
    u += 0x7fffu + ((u >> 16) & 1u);
    return (u16)(u >> 16);
}
__device__ __forceinline__ float bf2f(u16 h) {
    unsigned u = ((unsigned)h) << 16;
    return __builtin_bit_cast(float, u);
}
__device__ __forceinline__ void split_store(float v, u16* ph, u16* pl) {
    u16 h = f2bf(v);
    *ph = h;
    *pl = f2bf(v - bf2f(h));
}
__device__ __forceinline__ u16 f2h(float v) {
    return __builtin_bit_cast(u16, (_Float16)v);
}
__device__ __forceinline__ int rfl(int v) { return __builtin_amdgcn_readfirstlane(v); }
__device__ __forceinline__ int swz(int bx, int G) { return (bx & 7) * (G >> 3) + (bx >> 3); }

// pack fp32 w[27][Cin][Cout] -> frags, layout [tap][nt][kc][lane][8].
// Layers 0-4: bf16 hi/lo. Layer 5: fp16 hi/lo (consumed by the fp16 L5 kernel).
// blockIdx.y==6: split x into Xh/Xl bf16 (+zero page at blockIdx.x==64).
__global__ __launch_bounds__(256) void pack_all(
    const float* __restrict__ x, float* __restrict__ zf,
    u16* __restrict__ Xh, u16* __restrict__ Xl,
    const float* __restrict__ w0_, const float* __restrict__ w1_,
    const float* __restrict__ w2_, const float* __restrict__ w3_,
    const float* __restrict__ w4_, const float* __restrict__ w5_,
    u16* s0h, u16* s0l, u16* s1h, u16* s1l, u16* s2h, u16* s2l,
    u16* s3h, u16* s3l, u16* s4h, u16* s4l, u16* s5h, u16* s5l)
{
    if (blockIdx.y == 6) {
        if (blockIdx.x < 64) {
            const int i = (blockIdx.x * 256 + threadIdx.x) * 4;
            const float4 v = *(const float4*)(x + i);
            split_store(v.x, Xh + i,     Xl + i);
            split_store(v.y, Xh + i + 1, Xl + i + 1);
            split_store(v.z, Xh + i + 2, Xl + i + 2);
            split_store(v.w, Xh + i + 3, Xl + i + 3);
        } else if (blockIdx.x == 64) {
            ((float4*)zf)[threadIdx.x] = make_float4(0.f, 0.f, 0.f, 0.f);
        }
        return;
    }
    const float* w; u16 *bh, *bl; int Cin, Cout, nNt;
    switch (blockIdx.y) {
        case 0: w = w0_; bh = s0h; bl = s0l; Cin = 128; Cout = 128; nNt = 8; break;
        case 1: w = w1_; bh = s1h; bl = s1l; Cin = 128; Cout = 128; nNt = 8; break;
        case 2: w = w2_; bh = s2h; bl = s2l; Cin = 128; Cout = 128; nNt = 8; break;
        case 3: w = w3_; bh = s3h; bl = s3l; Cin = 128; Cout = 128; nNt = 8; break;
        case 4: w = w4_; bh = s4h; bl = s4l; Cin = 128; Cout = 64;  nNt = 4; break;
        default:w = w5_; bh = s5h; bl = s5l; Cin = 64;  Cout = 3;   nNt = 1; break;
    }
    const bool f16 = (blockIdx.y == 5);
    const int KC = Cin >> 5;
    const int total = 27 * nNt * KC * 64;
    int t = blockIdx.x * 256 + threadIdx.x;
    if (t >= total) return;
    const int lane = t & 63;
    int r = t >> 6;
    const int kc = r % KC; r /= KC;
    const int nt = r % nNt; r /= nNt;
    const int tap = r;
    const int n  = nt * 16 + (lane & 15);
    const int k0 = kc * 32 + (lane >> 4) * 8;
    const size_t o = (size_t)t * 8;
    for (int j = 0; j < 8; ++j) {
        float v = (n < Cout) ? w[((size_t)tap * Cin + k0 + j) * Cout + n] : 0.f;
        if (f16) {
            const _Float16 h = (_Float16)v;
            bh[o + j] = __builtin_bit_cast(u16, h);
            bl[o + j] = f2h(v - (float)h);
        } else {
            const u16 h = f2bf(v);
            bh[o + j] = h;
            bl[o + j] = f2bf(v - bf2f(h));
        }
    }
}

// ---------- stride-1 MFMA conv, register-double-buffered K-loop (R7) ----------
template<int CIN, int MT, int NT, bool RELU>
__global__ __launch_bounds__(64) void conv_s1_mfma(
    const u16* __restrict__ Ah, const u16* __restrict__ Al,
    const u16* __restrict__ Bh, const u16* __restrict__ Bl,
    const float* __restrict__ bias, const u16* __restrict__ Z,
    u16* __restrict__ Yh, u16* __restrict__ Yl,
    int D, int lD, int Cout, int nNtTot)
{
    constexpr int KC = CIN >> 5;
    const int lane = threadIdx.x;
    const int ml = lane & 15, kq = lane >> 4;
    const int M0 = swz(blockIdx.x, gridDim.x) * (MT * 16);
    const int N0t = blockIdx.y * NT;

    int vw[MT], vh[MT], vd[MT];
    #pragma unroll
    for (int mt = 0; mt < MT; ++mt) {
        const int vox = M0 + mt * 16 + ml;
        vw[mt] = vox & (D - 1); vh[mt] = (vox >> lD) & (D - 1); vd[mt] = vox >> (2 * lD);
    }

    f32x4 acc[MT][NT];
    #pragma unroll
    for (int nt = 0; nt < NT; ++nt) {
        const float bv = bias[(N0t + nt) * 16 + ml];
        #pragma unroll
        for (int mt = 0; mt < MT; ++mt) acc[mt][nt] = (f32x4){bv, bv, bv, bv};
    }

    const u16 *pah[MT], *pal[MT];
    size_t fb;
    auto set_tap = [&](int tap) {
        const int kd = tap / 9, kh = (tap % 9) / 3, kw = tap % 3;
        #pragma unroll
        for (int mt = 0; mt < MT; ++mt) {
            const int id = vd[mt] + kd - 1, ih = vh[mt] + kh - 1, iw = vw[mt] + kw - 1;
            const bool v = (unsigned)id < (unsigned)D && (unsigned)ih < (unsigned)D &&
                           (unsigned)iw < (unsigned)D;
            const size_t off = (size_t)((id * D + ih) * D + iw) * CIN;
            pah[mt] = v ? Ah + off : Z;
            pal[mt] = v ? Al + off : Z;
        }
        fb = ((size_t)tap * nNtTot + N0t) * KC;
    };

    bf16x8 fah[2][MT], fal[2][MT], fbh[2][NT], fbl[2][NT];
    auto load_frags = [&](int buf, int kc) {
        const int ko = kc * 32 + kq * 8;
        #pragma unroll
        for (int mt = 0; mt < MT; ++mt) {
            fah[buf][mt] = *(const bf16x8*)(pah[mt] + ko);
            fal[buf][mt] = *(const bf16x8*)(pal[mt] + ko);
        }
        #pragma unroll
        for (int nt = 0; nt < NT; ++nt) {
            const size_t fo = (fb + (size_t)nt * KC + kc) * 512 + lane * 8;
            fbh[buf][nt] = *(const bf16x8*)(Bh + fo);
            fbl[buf][nt] = *(const bf16x8*)(Bl + fo);
        }
    };

    set_tap(0);
    load_frags(0, 0);

    for (int tap = 0; tap < 27; ++tap) {
        #pragma unroll
        for (int kc = 0; kc < KC; ++kc) {
            const int cur = kc & 1, nxt = cur ^ 1;
            if (kc + 1 < KC) {
                load_frags(nxt, kc + 1);
            } else {
                set_tap(tap < 26 ? tap + 1 : 26);
                load_frags(nxt, 0);
            }
            #pragma unroll
            for (int mt = 0; mt < MT; ++mt)
            #pragma unroll
            for (int nt = 0; nt < NT; ++nt) {
                acc[mt][nt] = __builtin_amdgcn_mfma_f32_16x16x32_bf16(fah[cur][mt], fbh[cur][nt], acc[mt][nt], 0, 0, 0);
                acc[mt][nt] = __builtin_amdgcn_mfma_f32_16x16x32_bf16(fah[cur][mt], fbl[cur][nt], acc[mt][nt], 0, 0, 0);
                acc[mt][nt] = __builtin_amdgcn_mfma_f32_16x16x32_bf16(fal[cur][mt], fbh[cur][nt], acc[mt][nt], 0, 0, 0);
            }
        }
    }

    #pragma unroll
    for (int mt = 0; mt < MT; ++mt) {
        const int vox0 = M0 + mt * 16 + kq * 4;
        #pragma unroll
        for (int nt = 0; nt < NT; ++nt) {
            const int co = (N0t + nt) * 16 + ml;
            #pragma unroll
            for (int r = 0; r < 4; ++r) {
                float v = acc[mt][nt][r];
                if (RELU) v = fmaxf(v, 0.f);
                const size_t yo = (size_t)(vox0 + r) * Cout + co;
                split_store(v, Yh + yo, Yl + yo);
            }
        }
    }
}

// ---------- stride-1 conv with LDS-staged A (for the big D=32 layer) (R8, VST=72) ------
template<int D, int R, bool RELU>
__global__ __launch_bounds__(256) void conv_s1_lds(
    const u16* __restrict__ Ah, const u16* __restrict__ Al,
    const u16* __restrict__ Bh, const u16* __restrict__ Bl,
    const float* __restrict__ bias,
    u16* __restrict__ Yh, u16* __restrict__ Yl)
{
    constexpr int KC  = 4;
    constexpr int SH  = R + 2;
    constexpr int SW  = D + 2;
    constexpr int VST = 72;
    __shared__ u16 sm[3 * SH * SW * VST];

    const int tid  = threadIdx.x;
    const int lane = tid & 63, widx = tid >> 6;
    const int ml = lane & 15, kq = lane >> 4;

    const int bpp = D / R;
    const int lb  = swz(blockIdx.x, gridDim.x);
    const int d   = lb / bpp;
    const int h0  = (lb % bpp) * R;
    const int N0  = widx * 2;

    f32x4 acc[4][2];
    #pragma unroll
    for (int nt = 0; nt < 2; ++nt) {
        const float bv = bias[(N0 + nt) * 16 + ml];
        #pragma unroll
        for (int mt = 0; mt < 4; ++mt) acc[mt][nt] = (f32x4){bv, bv, bv, bv};
    }

    for (int i = tid; i < 3 * SH * 2 * 9; i += 256) {
        const int slot = i / 9, c8 = i % 9;
        const int side = slot & 1, rr = slot >> 1;
        const int dd = rr / SH, hh = rr % SH;
        *(bf16x8*)(sm + ((dd * SH + hh) * SW + (side ? SW - 1 : 0)) * VST + c8 * 8) =
            (bf16x8){0,0,0,0,0,0,0,0};
    }

    bf16x8 cbh[2], cbl[2], nbh[2], nbl[2];
    auto loadB = [&](bf16x8 (&dh)[2], bf16x8 (&dl)[2], int kc, int tap) {
        #pragma unroll
        for (int nt = 0; nt < 2; ++nt) {
            const size_t fo = (((size_t)tap * 8 + N0 + nt) * KC + kc) * 512 + lane * 8;
            dh[nt] = *(const bf16x8*)(Bh + fo);
            dl[nt] = *(const bf16x8*)(Bl + fo);
        }
    };
    loadB(cbh, cbl, 0, 0);

    for (int kc = 0; kc < KC; ++kc) {
        __syncthreads();
        constexpr int NCH = 3 * SH * D * 8;
        for (int i = tid; i < NCH; i += 256) {
            const int vox = i >> 3, c8 = i & 7;
            const int ww = vox % D;
            const int rr = vox / D;
            const int hh = rr % SH, dd = rr / SH;
            const int pd = d + dd - 1, ph = h0 + hh - 1;
            u16* dst = sm + ((dd * SH + hh) * SW + ww + 1) * VST + c8 * 8;
            if ((unsigned)pd < (unsigned)D && (unsigned)ph < (unsigned)D) {
                const u16* srcb = (c8 < 4) ? Ah : Al;
                const size_t g = ((size_t)(pd * D + ph) * D + ww) * 128 + kc * 32 + (c8 & 3) * 8;
                *(bf16x8*)dst = *(const bf16x8*)(srcb + g);
            } else {
                *(bf16x8*)dst = (bf16x8){0,0,0,0,0,0,0,0};
            }
        }
        __syncthreads();

        for (int tap = 0; tap < 27; ++tap) {
            const int lin = kc * 27 + tap + 1;
            if (lin < KC * 27) loadB(nbh, nbl, lin / 27, lin % 27);
            const int kd = tap / 9, kh = (tap % 9) / 3, kw = tap % 3;
            bf16x8 fa_h[4], fa_l[4];
            #pragma unroll
            for (int mt = 0; mt < 4; ++mt) {
                const int m = mt * 16 + ml;
                const int mh = m / D, mw = m % D;
                const u16* p = sm + (((kd * SH) + (mh + kh)) * SW + (mw + kw)) * VST;
                fa_h[mt] = *(const bf16x8*)(p + kq * 8);
                fa_l[mt] = *(const bf16x8*)(p + 32 + kq * 8);
            }
            #pragma unroll
            for (int mt = 0; mt < 4; ++mt)
            #pragma unroll
            for (int nt = 0; nt < 2; ++nt) {
                acc[mt][nt] = __builtin_amdgcn_mfma_f32_16x16x32_bf16(fa_h[mt], cbh[nt], acc[mt][nt], 0, 0, 0);
                acc[mt][nt] = __builtin_amdgcn_mfma_f32_16x16x32_bf16(fa_h[mt], cbl[nt], acc[mt][nt], 0, 0, 0);
                acc[mt][nt] = __builtin_amdgcn_mfma_f32_16x16x32_bf16(fa_l[mt], cbh[nt], acc[mt][nt], 0, 0, 0);
            }
            #pragma unroll
            for (int nt = 0; nt < 2; ++nt) { cbh[nt] = nbh[nt]; cbl[nt] = nbl[nt]; }
        }
    }

    const size_t M0 = (size_t)(d * D + h0) * D;
    #pragma unroll
    for (int mt = 0; mt < 4; ++mt) {
        #pragma unroll
        for (int nt = 0; nt < 2; ++nt) {
            const int co = (N0 + nt) * 16 + ml;
            #pragma unroll
            for (int r = 0; r < 4; ++r) {
                float v = acc[mt][nt][r];
                if (RELU) v = fmaxf(v, 0.f);
                const size_t yo = (M0 + mt * 16 + kq * 4 + r) * 128 + co;
                split_store(v, Yh + yo, Yl + yo);
            }
        }
    }
}

// ---------- stride-2 MFMA deconv (parity-decomposed), register-double-buffered (R7) ----
// F16OUT=true: epilogue stores a SINGLE fp16 per value into Yh (Yl unused) — used by L4,
// whose output P is consumed only by the fp16 L5 kernel.
template<int CIN, int MT, int NT, bool F16OUT = false>
__global__ __launch_bounds__(64) void deconv_s2_mfma(
    const u16* __restrict__ Ah, const u16* __restrict__ Al,
    const u16* __restrict__ Bh, const u16* __restrict__ Bl,
    const float* __restrict__ bias, const u16* __restrict__ Z,
    u16* __restrict__ Yh, u16* __restrict__ Yl,
    int Din, int lD, int Cout, int nNtTot)
{
    constexpr int KC = CIN >> 5;
    const int Dout = 2 * Din;
    const int lane = threadIdx.x;
    const int ml = lane & 15, kq = lane >> 4;
    const int M0 = swz(blockIdx.x, gridDim.x) * (MT * 16);
    const int N0t = blockIdx.y * NT;
    const int par = blockIdx.z;
    const int rd = (par >> 2) & 1, rh = (par >> 1) & 1, rw = par & 1;

    int sw[MT], sh[MT], sd[MT];
    #pragma unroll
    for (int mt = 0; mt < MT; ++mt) {
        const int sv = M0 + mt * 16 + ml;
        sw[mt] = sv & (Din - 1); sh[mt] = (sv >> lD) & (Din - 1); sd[mt] = sv >> (2 * lD);
    }

    f32x4 acc[MT][NT];
    #pragma unroll
    for (int nt = 0; nt < NT; ++nt) {
        const float bv = bias[(N0t + nt) * 16 + ml];
        #pragma unroll
        for (int mt = 0; mt < MT; ++mt) acc[mt][nt] = (f32x4){bv, bv, bv, bv};
    }

    const int lw = rw ? 0 : 1, lh = rh ? 0 : 1, ld2 = rd ? 0 : 1;
    const int ntap = 1 << (lw + lh + ld2);

    const u16 *pah[MT], *pal[MT];
    size_t fb;
    auto set_tap = [&](int t) {
        const int tw_ = t & ((1 << lw) - 1);
        const int th_ = (t >> lw) & ((1 << lh) - 1);
        const int td_ = t >> (lw + lh);
        const int kd = rd ? 1 : (td_ ? 0 : 2);
        const int kh = rh ? 1 : (th_ ? 0 : 2);
        const int kw = rw ? 1 : (tw_ ? 0 : 2);
        const int dd = rd ? 0 : -td_, dh = rh ? 0 : -th_, dw = rw ? 0 : -tw_;
        const int tap = (kd * 3 + kh) * 3 + kw;
        #pragma unroll
        for (int mt = 0; mt < MT; ++mt) {
            const int id = sd[mt] + dd, ih = sh[mt] + dh, iw = sw[mt] + dw;
            const bool v = id >= 0 && ih >= 0 && iw >= 0;
            const size_t off = (size_t)((id * Din + ih) * Din + iw) * CIN;
            pah[mt] = v ? Ah + off : Z;
            pal[mt] = v ? Al + off : Z;
        }
        fb = ((size_t)tap * nNtTot + N0t) * KC;
    };

    bf16x8 fah[2][MT], fal[2][MT], fbh[2][NT], fbl[2][NT];
    auto load_frags = [&](int buf, int kc) {
        const int ko = kc * 32 + kq * 8;
        #pragma unroll
        for (int mt = 0; mt < MT; ++mt) {
            fah[buf][mt] = *(const bf16x8*)(pah[mt] + ko);
            fal[buf][mt] = *(const bf16x8*)(pal[mt] + ko);
        }
        #pragma unroll
        for (int nt = 0; nt < NT; ++nt) {
            const size_t fo = (fb + (size_t)nt * KC + kc) * 512 + lane * 8;
            fbh[buf][nt] = *(const bf16x8*)(Bh + fo);
            fbl[buf][nt] = *(const bf16x8*)(Bl + fo);
        }
    };

    set_tap(0);
    load_frags(0, 0);

    for (int t = 0; t < ntap; ++t) {
        #pragma unroll
        for (int kc = 0; kc < KC; ++kc) {
            const int cur = kc & 1, nxt = cur ^ 1;
            if (kc + 1 < KC) {
                load_frags(nxt, kc + 1);
            } else {
                set_tap(t + 1 < ntap ? t + 1 : t);
                load_frags(nxt, 0);
            }
            #pragma unroll
            for (int mt = 0; mt < MT; ++mt)
            #pragma unroll
            for (int nt = 0; nt < NT; ++nt) {
                acc[mt][nt] = __builtin_amdgcn_mfma_f32_16x16x32_bf16(fah[cur][mt], fbh[cur][nt], acc[mt][nt], 0, 0, 0);
                acc[mt][nt] = __builtin_amdgcn_mfma_f32_16x16x32_bf16(fah[cur][mt], fbl[cur][nt], acc[mt][nt], 0, 0, 0);
                acc[mt][nt] = __builtin_amdgcn_mfma_f32_16x16x32_bf16(fal[cur][mt], fbh[cur][nt], acc[mt][nt], 0, 0, 0);
            }
        }
    }

    #pragma unroll
    for (int mt = 0; mt < MT; ++mt) {
        #pragma unroll
        for (int r = 0; r < 4; ++r) {
            const int sv = M0 + mt * 16 + kq * 4 + r;
            const int svw = sv & (Din - 1), svh = (sv >> lD) & (Din - 1), svd = sv >> (2 * lD);
            const int od = 2 * svd + rd, oh = 2 * svh + rh, ow = 2 * svw + rw;
            const size_t yb = (size_t)((od * Dout + oh) * Dout + ow) * Cout;
            #pragma unroll
            for (int nt = 0; nt < NT; ++nt) {
                const int co = (N0t + nt) * 16 + ml;
                if (F16OUT) Yh[yb + co] = f2h(acc[mt][nt][r]);
                else        split_store(acc[mt][nt][r], Yh + yb + co, Yl + yb + co);
            }
        }
    }
}

// ---------- final layer: D=64, Cin=64 -> Cout=3 (N pad 16), fp16 LDS (R14, VST=40) -----
// A = fp16 single (stored by L4), W = fp16 hi/lo (2 MFMA terms). Slab: 6 halo rows x
// 66 w-slots x [32 fp16 of current kc | 8 pad] = 31.7 KB, kc-sliced (3 kd x 2 kc phases).
#define L5_VST 40
#define L5_RST (66 * L5_VST)
__global__ __launch_bounds__(256) void conv_c3_lds(
    const u16* __restrict__ A,                 // fp16 bits, 64^3 x 64
    const u16* __restrict__ Bh, const u16* __restrict__ Bl,
    const float* __restrict__ bias, float* __restrict__ out)
{
    __shared__ u16 sm[6 * L5_RST];

    const int tid  = threadIdx.x;
    const int lane = tid & 63, widx = tid >> 6;
    const int ml = lane & 15, kq = lane >> 4;

    const int lb = swz(blockIdx.x, gridDim.x);
    const int d  = lb >> 4;
    const int h0 = (lb & 15) * 4;

    const float bv = (ml < 3) ? bias[ml] : 0.f;
    f32x4 acc[4];
    #pragma unroll
    for (int mt = 0; mt < 4; ++mt) acc[mt] = (f32x4){bv, bv, bv, bv};

    f16x8 cbh, cbl, nbh, nbl;
    auto loadB = [&](f16x8& dh, f16x8& dl, int tap, int kc) {
        const size_t fo = ((size_t)tap * 2 + kc) * 512 + lane * 8;
        dh = *(const f16x8*)(Bh + fo);
        dl = *(const f16x8*)(Bl + fo);
    };
    loadB(cbh, cbl, 0, 0);

    for (int kd = 0; kd < 3; ++kd) {
        const int pd = d + kd - 1;
        const bool vpd = (unsigned)pd < 64u;
        for (int kc = 0; kc < 2; ++kc) {
            __syncthreads();
            // stage 6 rows x 64 vox x 4 chunks (32 fp16 of this kc) = 1536 chunks
            #pragma unroll
            for (int i = 0; i < 6; ++i) {
                const int c = tid + 256 * i;
                const int r = c >> 8;                  // row slot 0..5
                const int rem = c & 255;
                const int vox = rem >> 2, c8 = rem & 3;
                const int hh = h0 - 1 + r;
                u16* dst = sm + r * L5_RST + (vox + 1) * L5_VST + c8 * 8;
                if (vpd && (unsigned)hh < 64u) {
                    const size_t g = (size_t)((pd * 64 + hh) * 64 + vox) * 64
                                   + kc * 32 + c8 * 8;
                    *(f16x8*)dst = *(const f16x8*)(A + g);
                } else {
                    *(f16x8*)dst = (f16x8){0,0,0,0,0,0,0,0};
                }
            }
            // w-edge pads (slots 0 and 65): 6 rows x 2 sides x 4 chunks = 48
            if (tid < 48) {
                const int r = tid >> 3, side = (tid >> 2) & 1, c8 = tid & 3;
                *(f16x8*)(sm + r * L5_RST + (side ? 65 : 0) * L5_VST + c8 * 8) =
                    (f16x8){0,0,0,0,0,0,0,0};
            }
            __syncthreads();

            #pragma unroll
            for (int t = 0; t < 9; ++t) {
                {   // prefetch next B (phase-linear index, clamped)
                    int lin = (kd * 2 + kc) * 9 + t + 1;
                    if (lin > 53) lin = 53;
                    const int Pn = lin / 9, tn = lin - Pn * 9;
                    loadB(nbh, nbl, (Pn >> 1) * 9 + tn, Pn & 1);
                }
                const int kh = t / 3, kw = t - kh * 3;
                const int slot = widx + kh;            // LDS row for h+kh-1
                #pragma unroll
                for (int mt = 0; mt < 4; ++mt) {
                    const u16* p = sm + slot * L5_RST + (mt * 16 + ml + kw) * L5_VST;
                    const f16x8 af = *(const f16x8*)(p + kq * 8);
                    acc[mt] = __builtin_amdgcn_mfma_f32_16x16x32_f16(af, cbh, acc[mt], 0, 0, 0);
                    acc[mt] = __builtin_amdgcn_mfma_f32_16x16x32_f16(af, cbl, acc[mt], 0, 0, 0);
                }
                cbh = nbh; cbl = nbl;
            }
        }
    }

    if (ml < 3) {
        const int h = h0 + widx;
        const size_t vb = (size_t)(d * 64 + h) * 64;
        #pragma unroll
        for (int mt = 0; mt < 4; ++mt)
        #pragma unroll
        for (int r = 0; r < 4; ++r)
            out[(vb + mt * 16 + kq * 4 + r) * 3 + ml] = acc[mt][r];
    }
}

extern "C" void kernel_launch(void* const* d_in, const int* in_sizes, int n_in,
                              void* d_out, int out_size, void* d_ws, size_t ws_size,
                              hipStream_t stream)
{
    const float* x   = (const float*)d_in[0];
    const float* w0  = (const float*)d_in[1];  const float* b0  = (const float*)d_in[2];
    const float* w00 = (const float*)d_in[3];  const float* b00 = (const float*)d_in[4];
    const float* w1  = (const float*)d_in[5];  const float* b1  = (const float*)d_in[6];
    const float* w10 = (const float*)d_in[7];  const float* b10 = (const float*)d_in[8];
    const float* w2  = (const float*)d_in[9];  const float* b2  = (const float*)d_in[10];
    const float* w20 = (const float*)d_in[11]; const float* b20 = (const float*)d_in[12];
    float* out = (float*)d_out;

    char* ws = (char*)d_ws;
    float* zf = (float*)ws;                      // 4 KB zero page
    u16*   Z  = (u16*)ws;
    u16* S4h = (u16*)(ws + 4096);                // durable packed weights (L4, L5)
    u16* S4l = S4h + 221184;
    u16* S5h = S4l + 221184;
    u16* S5l = S5h + 27648;
    u16* Qh  = (u16*)(ws + 1048576);             // 32^3 x 128
    u16* Ql  = Qh + 4194304;
    u16* Ph  = (u16*)(ws + 17825792);            // 64^3 x 64 (fp16 single for L5)
    u16* Pl  = Ph + 16777216;                    // bf16-lo for L0/L2 outputs only
    // transient packed weights (L0..L3) + X in the Pl tail (L4 no longer writes Pl at all)
    u16* S1h = (u16*)(ws + 60817408);
    u16* S1l = S1h + 442368;
    u16* S2h = S1l + 442368;
    u16* S2l = S2h + 442368;
    u16* S3h = S2l + 442368;
    u16* S3l = S3h + 442368;
    u16* S0h = S3l + 442368;
    u16* S0l = S0h + 442368;
    u16* Xh  = S0l + 442368;
    u16* Xl  = Xh + 65536;

    // pack weights (L0-L4 bf16 hi/lo, L5 fp16 hi/lo) + split x + zero page, one launch
    pack_all<<<dim3(216, 7), 256, 0, stream>>>(x, zf, Xh, Xl,
        w0, w00, w1, w10, w2, w20,
        S0h, S0l, S1h, S1l, S2h, S2l, S3h, S3l, S4h, S4l, S5h, S5l);

    // L0: X(8^3x128) --s2 MFMA--> P(16^3x128). Din=8, MT=2,NT=4.
    deconv_s2_mfma<128, 2, 4><<<dim3(16, 2, 8), 64, 0, stream>>>(
        Xh, Xl, S0h, S0l, b0, Z, Ph, Pl, 8, 3, 128, 8);

    // L1: P --s1+relu--> Q (D=16). MT=1,NT=2.
    conv_s1_mfma<128, 1, 2, true><<<dim3(256, 4), 64, 0, stream>>>(
        Ph, Pl, S1h, S1l, b00, Z, Qh, Ql, 16, 4, 128, 8);

    // L2: Q --s2--> P (Din=16). MT=2,NT=4.
    deconv_s2_mfma<128, 2, 4><<<dim3(128, 2, 8), 64, 0, stream>>>(
        Qh, Ql, S2h, S2l, b1, Z, Ph, Pl, 16, 4, 128, 8);

    // L3: P --s1+relu--> Q (D=32). LDS-staged A, 512 blocks x 4 waves.
    conv_s1_lds<32, 2, true><<<dim3(512), 256, 0, stream>>>(
        Ph, Pl, S3h, S3l, b10, Qh, Ql);

    // L4: Q --s2--> P (Din=32, Cout=64). MT=4,NT=4, fp16-single output (P feeds only L5).
    deconv_s2_mfma<128, 4, 4, true><<<dim3(512, 1, 8), 64, 0, stream>>>(
        Qh, Ql, S4h, S4l, b2, Z, Ph, Pl, 32, 5, 64, 4);

    // L5: P(fp16) --s1--> out. fp16 A x fp16-hi/lo W, LDS-staged, 1024 blocks.
    conv_c3_lds<<<dim3(1024), 256, 0, stream>>>(Ph, S5h, S5l, b20, out);
}

// Round 15
// 309.626 us; speedup vs baseline: 1.4315x; 1.1946x over previous
//
#include <hip/hip_runtime.h>

// Decoder via MFMA implicit GEMM, mixed-precision:
//   L0: bf16 hi/lo x bf16 hi/lo (3-term) — input X is fp32, keep 16-bit-effective A.
//   L1-L5: fp16-single activations x fp16 hi/lo weights (2-term) — R14 measured that an
//   fp16-single activation edge adds ZERO absmax error (error is one local bf16-scale
//   rounding, not accumulated edge noise), so all internal edges use it: A-traffic and
//   write-traffic halve, MFMA per step drops 3->2 terms.
// conv_transpose SAME:
//   stride1: O[o] = sum_k W[k] X[o+k-1]
//   stride2, parity r: r==1 -> tap kd=1,id=i ; r==0 -> kd=2,id=i and kd=0,id=i-1  (o=2i+r)
// Weights DHWIO [tap][ci][co], activations NDHWC.
// MFMA layouts (verified): A[m=lane&15][k=(lane>>4)*8+j], B[n=lane&15][k=(lane>>4)*8+j],
// D: col=lane&15, row=(lane>>4)*4+reg. C/D layout dtype-independent.
// LDS rule (R10): voxel slot stride must be a multiple of 8 u16 (16B) or b128 ops split.

typedef __attribute__((ext_vector_type(8))) short bf16x8;
typedef __attribute__((ext_vector_type(8))) _Float16 f16x8;
typedef __attribute__((ext_vector_type(4))) float f32x4;
typedef unsigned short u16;

__device__ __forceinline__ u16 f2bf(float f) {
    unsigned u = __builtin_bit_cast(unsigned, f);
    u += 0x7fffu + ((u >> 16) & 1u);
    return (u16)(u >> 16);
}
__device__ __forceinline__ float bf2f(u16 h) {
    unsigned u = ((unsigned)h) << 16;
    return __builtin_bit_cast(float, u);
}
__device__ __forceinline__ void split_store(float v, u16* ph, u16* pl) {
    u16 h = f2bf(v);
    *ph = h;
    *pl = f2bf(v - bf2f(h));
}
__device__ __forceinline__ u16 f2h(float v) {
    return __builtin_bit_cast(u16, (_Float16)v);
}
__device__ __forceinline__ int swz(int bx, int G) { return (bx & 7) * (G >> 3) + (bx >> 3); }

// pack fp32 w[27][Cin][Cout] -> frags [tap][nt][kc][lane][8].
// Layer 0: bf16 hi/lo. Layers 1-5: fp16 hi/lo. y==6: split x bf16 hi/lo + zero page.
__global__ __launch_bounds__(256) void pack_all(
    const float* __restrict__ x, float* __restrict__ zf,
    u16* __restrict__ Xh, u16* __restrict__ Xl,
    const float* __restrict__ w0_, const float* __restrict__ w1_,
    const float* __restrict__ w2_, const float* __restrict__ w3_,
    const float* __restrict__ w4_, const float* __restrict__ w5_,
    u16* s0h, u16* s0l, u16* s1h, u16* s1l, u16* s2h, u16* s2l,
    u16* s3h, u16* s3l, u16* s4h, u16* s4l, u16* s5h, u16* s5l)
{
    if (blockIdx.y == 6) {
        if (blockIdx.x < 64) {
            const int i = (blockIdx.x * 256 + threadIdx.x) * 4;
            const float4 v = *(const float4*)(x + i);
            split_store(v.x, Xh + i,     Xl + i);
            split_store(v.y, Xh + i + 1, Xl + i + 1);
            split_store(v.z, Xh + i + 2, Xl + i + 2);
            split_store(v.w, Xh + i + 3, Xl + i + 3);
        } else if (blockIdx.x == 64) {
            ((float4*)zf)[threadIdx.x] = make_float4(0.f, 0.f, 0.f, 0.f);
        }
        return;
    }
    const float* w; u16 *bh, *bl; int Cin, Cout, nNt;
    switch (blockIdx.y) {
        case 0: w = w0_; bh = s0h; bl = s0l; Cin = 128; Cout = 128; nNt = 8; break;
        case 1: w = w1_; bh = s1h; bl = s1l; Cin = 128; Cout = 128; nNt = 8; break;
        case 2: w = w2_; bh = s2h; bl = s2l; Cin = 128; Cout = 128; nNt = 8; break;
        case 3: w = w3_; bh = s3h; bl = s3l; Cin = 128; Cout = 128; nNt = 8; break;
        case 4: w = w4_; bh = s4h; bl = s4l; Cin = 128; Cout = 64;  nNt = 4; break;
        default:w = w5_; bh = s5h; bl = s5l; Cin = 64;  Cout = 3;   nNt = 1; break;
    }
    const bool f16 = (blockIdx.y >= 1);
    const int KC = Cin >> 5;
    const int total = 27 * nNt * KC * 64;
    int t = blockIdx.x * 256 + threadIdx.x;
    if (t >= total) return;
    const int lane = t & 63;
    int r = t >> 6;
    const int kc = r % KC; r /= KC;
    const int nt = r % nNt; r /= nNt;
    const int tap = r;
    const int n  = nt * 16 + (lane & 15);
    const int k0 = kc * 32 + (lane >> 4) * 8;
    const size_t o = (size_t)t * 8;
    for (int j = 0; j < 8; ++j) {
        float v = (n < Cout) ? w[((size_t)tap * Cin + k0 + j) * Cout + n] : 0.f;
        if (f16) {
            const _Float16 h = (_Float16)v;
            bh[o + j] = __builtin_bit_cast(u16, h);
            bl[o + j] = f2h(v - (float)h);
        } else {
            const u16 h = f2bf(v);
            bh[o + j] = h;
            bl[o + j] = f2bf(v - bf2f(h));
        }
    }
}

// ---------- L0 only: stride-2 bf16 hi/lo 3-term, fp16-single output (R7 + F16OUT) ------
template<int CIN, int MT, int NT>
__global__ __launch_bounds__(64) void deconv_s2_bf16(
    const u16* __restrict__ Ah, const u16* __restrict__ Al,
    const u16* __restrict__ Bh, const u16* __restrict__ Bl,
    const float* __restrict__ bias, const u16* __restrict__ Z,
    u16* __restrict__ Y, int Din, int lD, int Cout, int nNtTot)
{
    constexpr int KC = CIN >> 5;
    const int Dout = 2 * Din;
    const int lane = threadIdx.x;
    const int ml = lane & 15, kq = lane >> 4;
    const int M0 = swz(blockIdx.x, gridDim.x) * (MT * 16);
    const int N0t = blockIdx.y * NT;
    const int par = blockIdx.z;
    const int rd = (par >> 2) & 1, rh = (par >> 1) & 1, rw = par & 1;

    int sw[MT], sh[MT], sd[MT];
    #pragma unroll
    for (int mt = 0; mt < MT; ++mt) {
        const int sv = M0 + mt * 16 + ml;
        sw[mt] = sv & (Din - 1); sh[mt] = (sv >> lD) & (Din - 1); sd[mt] = sv >> (2 * lD);
    }

    f32x4 acc[MT][NT];
    #pragma unroll
    for (int nt = 0; nt < NT; ++nt) {
        const float bv = bias[(N0t + nt) * 16 + ml];
        #pragma unroll
        for (int mt = 0; mt < MT; ++mt) acc[mt][nt] = (f32x4){bv, bv, bv, bv};
    }

    const int lw = rw ? 0 : 1, lh = rh ? 0 : 1, ld2 = rd ? 0 : 1;
    const int ntap = 1 << (lw + lh + ld2);

    const u16 *pah[MT], *pal[MT];
    size_t fb;
    auto set_tap = [&](int t) {
        const int tw_ = t & ((1 << lw) - 1);
        const int th_ = (t >> lw) & ((1 << lh) - 1);
        const int td_ = t >> (lw + lh);
        const int kd = rd ? 1 : (td_ ? 0 : 2);
        const int kh = rh ? 1 : (th_ ? 0 : 2);
        const int kw = rw ? 1 : (tw_ ? 0 : 2);
        const int dd = rd ? 0 : -td_, dh = rh ? 0 : -th_, dw = rw ? 0 : -tw_;
        const int tap = (kd * 3 + kh) * 3 + kw;
        #pragma unroll
        for (int mt = 0; mt < MT; ++mt) {
            const int id = sd[mt] + dd, ih = sh[mt] + dh, iw = sw[mt] + dw;
            const bool v = id >= 0 && ih >= 0 && iw >= 0;
            const size_t off = (size_t)((id * Din + ih) * Din + iw) * CIN;
            pah[mt] = v ? Ah + off : Z;
            pal[mt] = v ? Al + off : Z;
        }
        fb = ((size_t)tap * nNtTot + N0t) * KC;
    };

    bf16x8 fah[2][MT], fal[2][MT], fbh[2][NT], fbl[2][NT];
    auto load_frags = [&](int buf, int kc) {
        const int ko = kc * 32 + kq * 8;
        #pragma unroll
        for (int mt = 0; mt < MT; ++mt) {
            fah[buf][mt] = *(const bf16x8*)(pah[mt] + ko);
            fal[buf][mt] = *(const bf16x8*)(pal[mt] + ko);
        }
        #pragma unroll
        for (int nt = 0; nt < NT; ++nt) {
            const size_t fo = (fb + (size_t)nt * KC + kc) * 512 + lane * 8;
            fbh[buf][nt] = *(const bf16x8*)(Bh + fo);
            fbl[buf][nt] = *(const bf16x8*)(Bl + fo);
        }
    };

    set_tap(0);
    load_frags(0, 0);

    for (int t = 0; t < ntap; ++t) {
        #pragma unroll
        for (int kc = 0; kc < KC; ++kc) {
            const int cur = kc & 1, nxt = cur ^ 1;
            if (kc + 1 < KC) {
                load_frags(nxt, kc + 1);
            } else {
                set_tap(t + 1 < ntap ? t + 1 : t);
                load_frags(nxt, 0);
            }
            #pragma unroll
            for (int mt = 0; mt < MT; ++mt)
            #pragma unroll
            for (int nt = 0; nt < NT; ++nt) {
                acc[mt][nt] = __builtin_amdgcn_mfma_f32_16x16x32_bf16(fah[cur][mt], fbh[cur][nt], acc[mt][nt], 0, 0, 0);
                acc[mt][nt] = __builtin_amdgcn_mfma_f32_16x16x32_bf16(fah[cur][mt], fbl[cur][nt], acc[mt][nt], 0, 0, 0);
                acc[mt][nt] = __builtin_amdgcn_mfma_f32_16x16x32_bf16(fal[cur][mt], fbh[cur][nt], acc[mt][nt], 0, 0, 0);
            }
        }
    }

    #pragma unroll
    for (int mt = 0; mt < MT; ++mt) {
        #pragma unroll
        for (int r = 0; r < 4; ++r) {
            const int sv = M0 + mt * 16 + kq * 4 + r;
            const int svw = sv & (Din - 1), svh = (sv >> lD) & (Din - 1), svd = sv >> (2 * lD);
            const int od = 2 * svd + rd, oh = 2 * svh + rh, ow = 2 * svw + rw;
            const size_t yb = (size_t)((od * Dout + oh) * Dout + ow) * Cout;
            #pragma unroll
            for (int nt = 0; nt < NT; ++nt)
                Y[yb + (N0t + nt) * 16 + ml] = f2h(acc[mt][nt][r]);
        }
    }
}

// ---------- fp16 stride-1 conv: A single, W hi/lo, 2-term; fp16-single out ----------
template<int CIN, int MT, int NT, bool RELU>
__global__ __launch_bounds__(64) void conv_s1_f16(
    const u16* __restrict__ A, const u16* __restrict__ Bh, const u16* __restrict__ Bl,
    const float* __restrict__ bias, const u16* __restrict__ Z,
    u16* __restrict__ Y, int D, int lD, int Cout, int nNtTot)
{
    constexpr int KC = CIN >> 5;
    const int lane = threadIdx.x;
    const int ml = lane & 15, kq = lane >> 4;
    const int M0 = swz(blockIdx.x, gridDim.x) * (MT * 16);
    const int N0t = blockIdx.y * NT;

    int vw[MT], vh[MT], vd[MT];
    #pragma unroll
    for (int mt = 0; mt < MT; ++mt) {
        const int vox = M0 + mt * 16 + ml;
        vw[mt] = vox & (D - 1); vh[mt] = (vox >> lD) & (D - 1); vd[mt] = vox >> (2 * lD);
    }

    f32x4 acc[MT][NT];
    #pragma unroll
    for (int nt = 0; nt < NT; ++nt) {
        const float bv = bias[(N0t + nt) * 16 + ml];
        #pragma unroll
        for (int mt = 0; mt < MT; ++mt) acc[mt][nt] = (f32x4){bv, bv, bv, bv};
    }

    const u16* pa[MT];
    size_t fb;
    auto set_tap = [&](int tap) {
        const int kd = tap / 9, kh = (tap % 9) / 3, kw = tap % 3;
        #pragma unroll
        for (int mt = 0; mt < MT; ++mt) {
            const int id = vd[mt] + kd - 1, ih = vh[mt] + kh - 1, iw = vw[mt] + kw - 1;
            const bool v = (unsigned)id < (unsigned)D && (unsigned)ih < (unsigned)D &&
                           (unsigned)iw < (unsigned)D;
            pa[mt] = v ? A + (size_t)((id * D + ih) * D + iw) * CIN : Z;
        }
        fb = ((size_t)tap * nNtTot + N0t) * KC;
    };

    f16x8 fa[2][MT], fbh[2][NT], fbl[2][NT];
    auto load_frags = [&](int buf, int kc) {
        const int ko = kc * 32 + kq * 8;
        #pragma unroll
        for (int mt = 0; mt < MT; ++mt)
            fa[buf][mt] = *(const f16x8*)(pa[mt] + ko);
        #pragma unroll
        for (int nt = 0; nt < NT; ++nt) {
            const size_t fo = (fb + (size_t)nt * KC + kc) * 512 + lane * 8;
            fbh[buf][nt] = *(const f16x8*)(Bh + fo);
            fbl[buf][nt] = *(const f16x8*)(Bl + fo);
        }
    };

    set_tap(0);
    load_frags(0, 0);

    for (int tap = 0; tap < 27; ++tap) {
        #pragma unroll
        for (int kc = 0; kc < KC; ++kc) {
            const int cur = kc & 1, nxt = cur ^ 1;
            if (kc + 1 < KC) {
                load_frags(nxt, kc + 1);
            } else {
                set_tap(tap < 26 ? tap + 1 : 26);
                load_frags(nxt, 0);
            }
            #pragma unroll
            for (int mt = 0; mt < MT; ++mt)
            #pragma unroll
            for (int nt = 0; nt < NT; ++nt) {
                acc[mt][nt] = __builtin_amdgcn_mfma_f32_16x16x32_f16(fa[cur][mt], fbh[cur][nt], acc[mt][nt], 0, 0, 0);
                acc[mt][nt] = __builtin_amdgcn_mfma_f32_16x16x32_f16(fa[cur][mt], fbl[cur][nt], acc[mt][nt], 0, 0, 0);
            }
        }
    }

    #pragma unroll
    for (int mt = 0; mt < MT; ++mt) {
        const int vox0 = M0 + mt * 16 + kq * 4;
        #pragma unroll
        for (int nt = 0; nt < NT; ++nt) {
            const int co = (N0t + nt) * 16 + ml;
            #pragma unroll
            for (int r = 0; r < 4; ++r) {
                float v = acc[mt][nt][r];
                if (RELU) v = fmaxf(v, 0.f);
                Y[(size_t)(vox0 + r) * Cout + co] = f2h(v);
            }
        }
    }
}

// ---------- fp16 stride-2 deconv (parity-decomposed), A single, W hi/lo, 2-term -------
template<int CIN, int MT, int NT>
__global__ __launch_bounds__(64) void deconv_s2_f16(
    const u16* __restrict__ A, const u16* __restrict__ Bh, const u16* __restrict__ Bl,
    const float* __restrict__ bias, const u16* __restrict__ Z,
    u16* __restrict__ Y, int Din, int lD, int Cout, int nNtTot)
{
    constexpr int KC = CIN >> 5;
    const int Dout = 2 * Din;
    const int lane = threadIdx.x;
    const int ml = lane & 15, kq = lane >> 4;
    const int M0 = swz(blockIdx.x, gridDim.x) * (MT * 16);
    const int N0t = blockIdx.y * NT;
    const int par = blockIdx.z;
    const int rd = (par >> 2) & 1, rh = (par >> 1) & 1, rw = par & 1;

    int sw[MT], sh[MT], sd[MT];
    #pragma unroll
    for (int mt = 0; mt < MT; ++mt) {
        const int sv = M0 + mt * 16 + ml;
        sw[mt] = sv & (Din - 1); sh[mt] = (sv >> lD) & (Din - 1); sd[mt] = sv >> (2 * lD);
    }

    f32x4 acc[MT][NT];
    #pragma unroll
    for (int nt = 0; nt < NT; ++nt) {
        const float bv = bias[(N0t + nt) * 16 + ml];
        #pragma unroll
        for (int mt = 0; mt < MT; ++mt) acc[mt][nt] = (f32x4){bv, bv, bv, bv};
    }

    const int lw = rw ? 0 : 1, lh = rh ? 0 : 1, ld2 = rd ? 0 : 1;
    const int ntap = 1 << (lw + lh + ld2);

    const u16* pa[MT];
    size_t fb;
    auto set_tap = [&](int t) {
        const int tw_ = t & ((1 << lw) - 1);
        const int th_ = (t >> lw) & ((1 << lh) - 1);
        const int td_ = t >> (lw + lh);
        const int kd = rd ? 1 : (td_ ? 0 : 2);
        const int kh = rh ? 1 : (th_ ? 0 : 2);
        const int kw = rw ? 1 : (tw_ ? 0 : 2);
        const int dd = rd ? 0 : -td_, dh = rh ? 0 : -th_, dw = rw ? 0 : -tw_;
        const int tap = (kd * 3 + kh) * 3 + kw;
        #pragma unroll
        for (int mt = 0; mt < MT; ++mt) {
            const int id = sd[mt] + dd, ih = sh[mt] + dh, iw = sw[mt] + dw;
            const bool v = id >= 0 && ih >= 0 && iw >= 0;
            pa[mt] = v ? A + (size_t)((id * Din + ih) * Din + iw) * CIN : Z;
        }
        fb = ((size_t)tap * nNtTot + N0t) * KC;
    };

    f16x8 fa[2][MT], fbh[2][NT], fbl[2][NT];
    auto load_frags = [&](int buf, int kc) {
        const int ko = kc * 32 + kq * 8;
        #pragma unroll
        for (int mt = 0; mt < MT; ++mt)
            fa[buf][mt] = *(const f16x8*)(pa[mt] + ko);
        #pragma unroll
        for (int nt = 0; nt < NT; ++nt) {
            const size_t fo = (fb + (size_t)nt * KC + kc) * 512 + lane * 8;
            fbh[buf][nt] = *(const f16x8*)(Bh + fo);
            fbl[buf][nt] = *(const f16x8*)(Bl + fo);
        }
    };

    set_tap(0);
    load_frags(0, 0);

    for (int t = 0; t < ntap; ++t) {
        #pragma unroll
        for (int kc = 0; kc < KC; ++kc) {
            const int cur = kc & 1, nxt = cur ^ 1;
            if (kc + 1 < KC) {
                load_frags(nxt, kc + 1);
            } else {
                set_tap(t + 1 < ntap ? t + 1 : t);
                load_frags(nxt, 0);
            }
            #pragma unroll
            for (int mt = 0; mt < MT; ++mt)
            #pragma unroll
            for (int nt = 0; nt < NT; ++nt) {
                acc[mt][nt] = __builtin_amdgcn_mfma_f32_16x16x32_f16(fa[cur][mt], fbh[cur][nt], acc[mt][nt], 0, 0, 0);
                acc[mt][nt] = __builtin_amdgcn_mfma_f32_16x16x32_f16(fa[cur][mt], fbl[cur][nt], acc[mt][nt], 0, 0, 0);
            }
        }
    }

    #pragma unroll
    for (int mt = 0; mt < MT; ++mt) {
        #pragma unroll
        for (int r = 0; r < 4; ++r) {
            const int sv = M0 + mt * 16 + kq * 4 + r;
            const int svw = sv & (Din - 1), svh = (sv >> lD) & (Din - 1), svd = sv >> (2 * lD);
            const int od = 2 * svd + rd, oh = 2 * svh + rh, ow = 2 * svw + rw;
            const size_t yb = (size_t)((od * Dout + oh) * Dout + ow) * Cout;
            #pragma unroll
            for (int nt = 0; nt < NT; ++nt)
                Y[yb + (N0t + nt) * 16 + ml] = f2h(acc[mt][nt][r]);
        }
    }
}

// ---------- L3: fp16 stride-1 with LDS-staged A (D=32, R=2), VST=40 ----------
template<int D, int R, bool RELU>
__global__ __launch_bounds__(256) void conv_s1_lds_f16(
    const u16* __restrict__ A, const u16* __restrict__ Bh, const u16* __restrict__ Bl,
    const float* __restrict__ bias, u16* __restrict__ Y)
{
    constexpr int KC  = 4;
    constexpr int SH  = R + 2;
    constexpr int SW  = D + 2;
    constexpr int VST = 40;               // 32 fp16 (this kc) + 8 pad — 16B-aligned
    __shared__ u16 sm[3 * SH * SW * VST]; // 32,640 B

    const int tid  = threadIdx.x;
    const int lane = tid & 63, widx = tid >> 6;
    const int ml = lane & 15, kq = lane >> 4;

    const int bpp = D / R;
    const int lb  = swz(blockIdx.x, gridDim.x);
    const int d   = lb / bpp;
    const int h0  = (lb % bpp) * R;
    const int N0  = widx * 2;

    f32x4 acc[4][2];
    #pragma unroll
    for (int nt = 0; nt < 2; ++nt) {
        const float bv = bias[(N0 + nt) * 16 + ml];
        #pragma unroll
        for (int mt = 0; mt < 4; ++mt) acc[mt][nt] = (f32x4){bv, bv, bv, bv};
    }

    // zero w-edge pad slots (slot 0 and SW-1), 4 chunks each, once
    for (int i = tid; i < 3 * SH * 2 * 4; i += 256) {
        const int slot = i >> 2, c8 = i & 3;
        const int side = slot & 1, rr = slot >> 1;
        const int dd = rr / SH, hh = rr % SH;
        *(f16x8*)(sm + ((dd * SH + hh) * SW + (side ? SW - 1 : 0)) * VST + c8 * 8) =
            (f16x8){0,0,0,0,0,0,0,0};
    }

    f16x8 cbh[2], cbl[2], nbh[2], nbl[2];
    auto loadB = [&](f16x8 (&dh)[2], f16x8 (&dl)[2], int kc, int tap) {
        #pragma unroll
        for (int nt = 0; nt < 2; ++nt) {
            const size_t fo = (((size_t)tap * 8 + N0 + nt) * KC + kc) * 512 + lane * 8;
            dh[nt] = *(const f16x8*)(Bh + fo);
            dl[nt] = *(const f16x8*)(Bl + fo);
        }
    };
    loadB(cbh, cbl, 0, 0);

    for (int kc = 0; kc < KC; ++kc) {
        __syncthreads();
        // stage 3 x SH x D voxels x 4 chunks (32 fp16 of this kc)
        constexpr int NCH = 3 * SH * D * 4;
        for (int i = tid; i < NCH; i += 256) {
            const int vox = i >> 2, c8 = i & 3;
            const int ww = vox % D;
            const int rr = vox / D;
            const int hh = rr % SH, dd = rr / SH;
            const int pd = d + dd - 1, ph = h0 + hh - 1;
            u16* dst = sm + ((dd * SH + hh) * SW + ww + 1) * VST + c8 * 8;
            if ((unsigned)pd < (unsigned)D && (unsigned)ph < (unsigned)D) {
                const size_t g = ((size_t)(pd * D + ph) * D + ww) * 128 + kc * 32 + c8 * 8;
                *(f16x8*)dst = *(const f16x8*)(A + g);
            } else {
                *(f16x8*)dst = (f16x8){0,0,0,0,0,0,0,0};
            }
        }
        __syncthreads();

        for (int tap = 0; tap < 27; ++tap) {
            const int lin = kc * 27 + tap + 1;
            if (lin < KC * 27) loadB(nbh, nbl, lin / 27, lin % 27);
            const int kd = tap / 9, kh = (tap % 9) / 3, kw = tap % 3;
            f16x8 fa[4];
            #pragma unroll
            for (int mt = 0; mt < 4; ++mt) {
                const int m = mt * 16 + ml;
                const int mh = m / D, mw = m % D;
                fa[mt] = *(const f16x8*)(sm + (((kd * SH) + (mh + kh)) * SW + (mw + kw)) * VST
                                          + kq * 8);
            }
            #pragma unroll
            for (int mt = 0; mt < 4; ++mt)
            #pragma unroll
            for (int nt = 0; nt < 2; ++nt) {
                acc[mt][nt] = __builtin_amdgcn_mfma_f32_16x16x32_f16(fa[mt], cbh[nt], acc[mt][nt], 0, 0, 0);
                acc[mt][nt] = __builtin_amdgcn_mfma_f32_16x16x32_f16(fa[mt], cbl[nt], acc[mt][nt], 0, 0, 0);
            }
            #pragma unroll
            for (int nt = 0; nt < 2; ++nt) { cbh[nt] = nbh[nt]; cbl[nt] = nbl[nt]; }
        }
    }

    const size_t M0 = (size_t)(d * D + h0) * D;
    #pragma unroll
    for (int mt = 0; mt < 4; ++mt) {
        #pragma unroll
        for (int nt = 0; nt < 2; ++nt) {
            const int co = (N0 + nt) * 16 + ml;
            #pragma unroll
            for (int r = 0; r < 4; ++r) {
                float v = acc[mt][nt][r];
                if (RELU) v = fmaxf(v, 0.f);
                Y[(M0 + mt * 16 + kq * 4 + r) * 128 + co] = f2h(v);
            }
        }
    }
}

// ---------- L5: D=64, Cin=64 -> Cout=3 (N pad 16), fp16 LDS (R14, VST=40) ----------
#define L5_VST 40
#define L5_RST (66 * L5_VST)
__global__ __launch_bounds__(256) void conv_c3_lds(
    const u16* __restrict__ A,
    const u16* __restrict__ Bh, const u16* __restrict__ Bl,
    const float* __restrict__ bias, float* __restrict__ out)
{
    __shared__ u16 sm[6 * L5_RST];

    const int tid  = threadIdx.x;
    const int lane = tid & 63, widx = tid >> 6;
    const int ml = lane & 15, kq = lane >> 4;

    const int lb = swz(blockIdx.x, gridDim.x);
    const int d  = lb >> 4;
    const int h0 = (lb & 15) * 4;

    const float bv = (ml < 3) ? bias[ml] : 0.f;
    f32x4 acc[4];
    #pragma unroll
    for (int mt = 0; mt < 4; ++mt) acc[mt] = (f32x4){bv, bv, bv, bv};

    f16x8 cbh, cbl, nbh, nbl;
    auto loadB = [&](f16x8& dh, f16x8& dl, int tap, int kc) {
        const size_t fo = ((size_t)tap * 2 + kc) * 512 + lane * 8;
        dh = *(const f16x8*)(Bh + fo);
        dl = *(const f16x8*)(Bl + fo);
    };
    loadB(cbh, cbl, 0, 0);

    for (int kd = 0; kd < 3; ++kd) {
        const int pd = d + kd - 1;
        const bool vpd = (unsigned)pd < 64u;
        for (int kc = 0; kc < 2; ++kc) {
            __syncthreads();
            #pragma unroll
            for (int i = 0; i < 6; ++i) {
                const int c = tid + 256 * i;
                const int r = c >> 8;
                const int rem = c & 255;
                const int vox = rem >> 2, c8 = rem & 3;
                const int hh = h0 - 1 + r;
                u16* dst = sm + r * L5_RST + (vox + 1) * L5_VST + c8 * 8;
                if (vpd && (unsigned)hh < 64u) {
                    const size_t g = (size_t)((pd * 64 + hh) * 64 + vox) * 64
                                   + kc * 32 + c8 * 8;
                    *(f16x8*)dst = *(const f16x8*)(A + g);
                } else {
                    *(f16x8*)dst = (f16x8){0,0,0,0,0,0,0,0};
                }
            }
            if (tid < 48) {
                const int r = tid >> 3, side = (tid >> 2) & 1, c8 = tid & 3;
                *(f16x8*)(sm + r * L5_RST + (side ? 65 : 0) * L5_VST + c8 * 8) =
                    (f16x8){0,0,0,0,0,0,0,0};
            }
            __syncthreads();

            #pragma unroll
            for (int t = 0; t < 9; ++t) {
                {
                    int lin = (kd * 2 + kc) * 9 + t + 1;
                    if (lin > 53) lin = 53;
                    const int Pn = lin / 9, tn = lin - Pn * 9;
                    loadB(nbh, nbl, (Pn >> 1) * 9 + tn, Pn & 1);
                }
                const int kh = t / 3, kw = t - kh * 3;
                const int slot = widx + kh;
                #pragma unroll
                for (int mt = 0; mt < 4; ++mt) {
                    const u16* p = sm + slot * L5_RST + (mt * 16 + ml + kw) * L5_VST;
                    const f16x8 af = *(const f16x8*)(p + kq * 8);
                    acc[mt] = __builtin_amdgcn_mfma_f32_16x16x32_f16(af, cbh, acc[mt], 0, 0, 0);
                    acc[mt] = __builtin_amdgcn_mfma_f32_16x16x32_f16(af, cbl, acc[mt], 0, 0, 0);
                }
                cbh = nbh; cbl = nbl;
            }
        }
    }

    if (ml < 3) {
        const int h = h0 + widx;
        const size_t vb = (size_t)(d * 64 + h) * 64;
        #pragma unroll
        for (int mt = 0; mt < 4; ++mt)
        #pragma unroll
        for (int r = 0; r < 4; ++r)
            out[(vb + mt * 16 + kq * 4 + r) * 3 + ml] = acc[mt][r];
    }
}

extern "C" void kernel_launch(void* const* d_in, const int* in_sizes, int n_in,
                              void* d_out, int out_size, void* d_ws, size_t ws_size,
                              hipStream_t stream)
{
    const float* x   = (const float*)d_in[0];
    const float* w0  = (const float*)d_in[1];  const float* b0  = (const float*)d_in[2];
    const float* w00 = (const float*)d_in[3];  const float* b00 = (const float*)d_in[4];
    const float* w1  = (const float*)d_in[5];  const float* b1  = (const float*)d_in[6];
    const float* w10 = (const float*)d_in[7];  const float* b10 = (const float*)d_in[8];
    const float* w2  = (const float*)d_in[9];  const float* b2  = (const float*)d_in[10];
    const float* w20 = (const float*)d_in[11]; const float* b20 = (const float*)d_in[12];
    float* out = (float*)d_out;

    char* ws = (char*)d_ws;
    float* zf = (float*)ws;                      // 4 KB zero page
    u16*   Z  = (u16*)ws;
    u16* S4h = (u16*)(ws + 4096);                // durable packed weights (L4, L5)
    u16* S4l = S4h + 221184;
    u16* S5h = S4l + 221184;
    u16* S5l = S5h + 27648;
    u16* Qh  = (u16*)(ws + 1048576);             // fp16 activations (L1/L3 out)
    u16* Ql  = Qh + 4194304;                     // unused (layout kept from R13)
    u16* Ph  = (u16*)(ws + 17825792);            // fp16 activations (L0/L2/L4 out)
    u16* Pl  = Ph + 16777216;                    // unused by activations
    u16* S1h = (u16*)(ws + 60817408);            // transient packed weights (Pl tail)
    u16* S1l = S1h + 442368;
    u16* S2h = S1l + 442368;
    u16* S2l = S2h + 442368;
    u16* S3h = S2l + 442368;
    u16* S3l = S3h + 442368;
    u16* S0h = S3l + 442368;
    u16* S0l = S0h + 442368;
    u16* Xh  = S0l + 442368;
    u16* Xl  = Xh + 65536;

    // pack weights (L0 bf16 h/l, L1-L5 fp16 h/l) + split x + zero page, one launch
    pack_all<<<dim3(216, 7), 256, 0, stream>>>(x, zf, Xh, Xl,
        w0, w00, w1, w10, w2, w20,
        S0h, S0l, S1h, S1l, S2h, S2l, S3h, S3l, S4h, S4l, S5h, S5l);

    // L0: X(8^3x128) --s2 bf16 3-term--> P(16^3x128 fp16). Din=8, MT=2,NT=4.
    deconv_s2_bf16<128, 2, 4><<<dim3(16, 2, 8), 64, 0, stream>>>(
        Xh, Xl, S0h, S0l, b0, Z, Ph, 8, 3, 128, 8);

    // L1: P --s1+relu--> Q (D=16). fp16 2-term, MT=1,NT=2.
    conv_s1_f16<128, 1, 2, true><<<dim3(256, 4), 64, 0, stream>>>(
        Ph, S1h, S1l, b00, Z, Qh, 16, 4, 128, 8);

    // L2: Q --s2--> P (Din=16). fp16 2-term, MT=2,NT=4.
    deconv_s2_f16<128, 2, 4><<<dim3(128, 2, 8), 64, 0, stream>>>(
        Qh, S2h, S2l, b1, Z, Ph, 16, 4, 128, 8);

    // L3: P --s1+relu--> Q (D=32). fp16 LDS-staged, 512 blocks x 4 waves.
    conv_s1_lds_f16<32, 2, true><<<dim3(512), 256, 0, stream>>>(
        Ph, S3h, S3l, b10, Qh);

    // L4: Q --s2--> P (Din=32, Cout=64). fp16 2-term, MT=4,NT=4.
    deconv_s2_f16<128, 4, 4><<<dim3(512, 1, 8), 64, 0, stream>>>(
        Qh, S4h, S4l, b2, Z, Ph, 32, 5, 64, 4);

    // L5: P(fp16) --s1--> out. fp16 LDS-staged, 1024 blocks.
    conv_c3_lds<<<dim3(1024), 256, 0, stream>>>(Ph, S5h, S5l, b20, out);
}